// Round 9
// baseline (10613.606 us; speedup 1.0000x reference)
//
#include <hip/hip_runtime.h>

typedef _Float16 f16;
typedef _Float16 f16x8 __attribute__((ext_vector_type(8)));
typedef float f32x4 __attribute__((ext_vector_type(4)));

#define STEPS 512
#define BATCHN 256
#define HID 1024
#define EMBN 100
#define KTOT 1152
#define XPAD 128
#define NBLK 256

__device__ __forceinline__ float sigm(float x){ return 1.f/(1.f+__expf(-x)); }
__device__ __forceinline__ float tanh_f(float x){
    float e = __expf(2.f*fabsf(x));
    float r = 1.f - 2.f/(e+1.f);
    return x >= 0.f ? r : -r;
}
// select {a0,a1,a2,a3}[idx] without runtime-indexed array (rule #20)
__device__ __forceinline__ float pick4(float a0, float a1, float a2, float a3, int idx){
    float t0 = (idx & 1) ? a1 : a0;
    float t1 = (idx & 1) ? a3 : a2;
    return (idx & 2) ? t1 : t0;
}

// Pack W_h(1024 rows)+W_x(100)+pad -> WT[4096][1152] f16 hi/lo.
// Col J = cg*64 + ct*16 + g*4 + um -> unit u = cg*16 + ct*4 + um. Also bias[J].
__global__ void pack_w(const float* __restrict__ Whi_, const float* __restrict__ Whf_,
                       const float* __restrict__ Who_, const float* __restrict__ Whc_,
                       const float* __restrict__ Wxi_, const float* __restrict__ Wxf_,
                       const float* __restrict__ Wxo_, const float* __restrict__ Wxc_,
                       const float* __restrict__ bi_, const float* __restrict__ bf_,
                       const float* __restrict__ bo_, const float* __restrict__ bc_,
                       f16* __restrict__ WThi, f16* __restrict__ WTlo, float* __restrict__ biasP)
{
    int J = blockIdx.x;                 // 0..4095
    int cg = J >> 6, ct = (J >> 4) & 3, g = (J >> 2) & 3, um = J & 3;
    int u = cg*16 + ct*4 + um;
    const float* Wh = (g==0)?Whi_:(g==1)?Whf_:(g==2)?Who_:Whc_;
    const float* Wx = (g==0)?Wxi_:(g==1)?Wxf_:(g==2)?Wxo_:Wxc_;
    for (int k = threadIdx.x; k < KTOT; k += blockDim.x){
        float v = 0.f;
        if (k < 1024)       v = Wh[(size_t)k*HID + u];
        else if (k < 1124)  v = Wx[(size_t)(k-1024)*HID + u];
        f16 hi = (f16)v;
        WThi[(size_t)J*KTOT + k] = hi;
        WTlo[(size_t)J*KTOT + k] = (f16)(v - (float)hi);
    }
    if (threadIdx.x == 0){
        const float* bb = (g==0)?bi_:(g==1)?bf_:(g==2)?bo_:bc_;
        biasP[J] = bb[u];
    }
}

__global__ void pack_x(const int* __restrict__ tokens, const float* __restrict__ emb,
                       f16* __restrict__ Xbuf)
{
    int bid = blockIdx.x;               // t*256 + row
    int t = bid >> 8, row = bid & 255;
    int tok = tokens[(size_t)row*STEPS + t];
    int kx = threadIdx.x;               // 0..127
    float v = (kx < EMBN) ? emb[(size_t)tok*EMBN + kx] : 0.f;
    Xbuf[(size_t)bid*XPAD + kx] = (f16)v;
}

__global__ void pack_h0(const float* __restrict__ H0, f16* __restrict__ Hb)
{
    int i = blockIdx.x*blockDim.x + threadIdx.x;
    if (i < BATCHN*HID) Hb[i] = (f16)H0[i];
}

// Async DMA: 16B/lane, LDS dest = wave-uniform base + lane*16 (linear).
// H and X: aux=0 (plain cached). Freshness of H comes from the per-step
// agent-acquire fence (buffer_inv): post-inv misses refill from the LLC,
// which is authoritative because H stores are sc1 write-through.
#define DMA16(gsrc, ldst, AUX)                                                     \
    __builtin_amdgcn_global_load_lds(                                              \
        (const __attribute__((address_space(1))) unsigned int*)(gsrc),             \
        (__attribute__((address_space(3))) unsigned int*)(ldst), 16, 0, (AUX))

// Stage one k-tile (64 rows x 32 k, 4KB) into wave-private slot via 4 DMA chunks.
// Chunk c: lane l -> row c*16+(l>>2), dst granule l&3, src granule (l&3)^(row&3)
// (source-side swizzle; DMA dest stays linear per m104/m173).
#define ISSUE_DMA(kt_, slot_) do {                                                 \
    const int kb_ = w*288 + (kt_)*32;                                              \
    f16* d0_ = AldsW + (slot_)*2048;                                               \
    if (kb_ < 1024){                                                               \
        DMA16(Hrd + srcH0 + kb_, d0_,        0);                                   \
        DMA16(Hrd + srcH1 + kb_, d0_ + 512,  0);                                   \
        DMA16(Hrd + srcH2 + kb_, d0_ + 1024, 0);                                   \
        DMA16(Hrd + srcH3 + kb_, d0_ + 1536, 0);                                   \
    } else {                                                                       \
        const int xo_ = kb_ - 1024;                                                \
        DMA16(Xrow + srcX0 + xo_, d0_,        0);                                  \
        DMA16(Xrow + srcX1 + xo_, d0_ + 512,  0);                                  \
        DMA16(Xrow + srcX2 + xo_, d0_ + 1024, 0);                                  \
        DMA16(Xrow + srcX3 + xo_, d0_ + 1536, 0);                                  \
    }                                                                              \
} while(0)

#define WAITV(kt_) do {                                                            \
    if ((kt_) < 7)       asm volatile("s_waitcnt vmcnt(8)" ::: "memory");          \
    else if ((kt_) == 7) asm volatile("s_waitcnt vmcnt(4)" ::: "memory");          \
    else                 asm volatile("s_waitcnt vmcnt(0)" ::: "memory");          \
    __builtin_amdgcn_sched_barrier(0);                                             \
} while(0)

#define LOADA(slot_, AF) do {                                                      \
    AF[0] = *(const f16x8*)(AldsW + (slot_)*2048 + ofsA0);                         \
    AF[1] = *(const f16x8*)(AldsW + (slot_)*2048 + ofsA1);                         \
    AF[2] = *(const f16x8*)(AldsW + (slot_)*2048 + ofsA2);                         \
    AF[3] = *(const f16x8*)(AldsW + (slot_)*2048 + ofsA3);                         \
} while(0)

#define MM(kt_, AF) do {                                                           \
    _Pragma("unroll")                                                              \
    for (int q_ = 0; q_ < 4; q_++){                                                \
        _Pragma("unroll")                                                          \
        for (int ct_ = 0; ct_ < 4; ct_++){                                         \
            acc[q_][ct_] = __builtin_amdgcn_mfma_f32_16x16x32_f16(AF[q_], Bf[kt_][0][ct_], acc[q_][ct_], 0,0,0); \
            acc[q_][ct_] = __builtin_amdgcn_mfma_f32_16x16x32_f16(AF[q_], Bf[kt_][1][ct_], acc[q_][ct_], 0,0,0); \
        }                                                                          \
    }                                                                              \
} while(0)

// Persistent LSTM: 256 blocks (4 bg x 64 cg) x 256 threads, 1/CU.
// Weights f16 hi/lo in VGPR+AGPR (288/lane). A staged via async global_load_lds
// (3-deep kt ring). H publishes sc1 (LLC authoritative); H reads PLAIN-cached
// behind a per-wave agent-acquire fence (buffer_inv) each step, so the 32+
// blocks per XCD sharing a bg slice broadcast through their XCD L2 instead of
// all hitting the LLC (round-4/8 floor: 37.6MB/step @ ~2.8TB/s = ~14us/step).
__global__ __launch_bounds__(256, 1) void lstm_main(
    const f16* __restrict__ WThi, const f16* __restrict__ WTlo,
    const f16* __restrict__ Xbuf, const float* __restrict__ biasP,
    const float* __restrict__ C0, f16* __restrict__ Ha, f16* __restrict__ Hb,
    const float* __restrict__ dw, const float* __restrict__ db,
    float* __restrict__ out, unsigned* __restrict__ flags)
{
    __shared__ __align__(16) f16 Alds[4*3*2048];   // 48KB; red overlays [0,16KB)
    __shared__ int s_bail;
    f32x4* red = (f32x4*)Alds;                      // [owner4][ct4][lane64]

    const int bid = blockIdx.x;
    const int bg = bid & 3, cg = bid >> 2;
    const int tid = threadIdx.x;
    const int w = tid >> 6, l = tid & 63, lr = l & 15, lhi = l >> 4;
    const int um = l & 3, gs = lr >> 2;
    if (tid == 0) s_bail = 0;

    f16* AldsW = Alds + w*3*2048;

    // ---- persistent weights: 9 kt x {hi,lo} x 4 ct = 288 VGPR/AGPR per lane ----
    f16x8 Bf[9][2][4];
    #pragma unroll
    for (int kt = 0; kt < 9; kt++){
        int k0 = w*288 + kt*32 + lhi*8;
        #pragma unroll
        for (int ct = 0; ct < 4; ct++){
            size_t off = (size_t)(cg*64 + ct*16 + lr)*KTOT + k0;
            Bf[kt][0][ct] = *(const f16x8*)(WThi + off);
            Bf[kt][1][ct] = *(const f16x8*)(WTlo + off);
        }
    }
    float bs[4][4];                      // [ct][gate]
    #pragma unroll
    for (int ct = 0; ct < 4; ct++)
        #pragma unroll
        for (int g = 0; g < 4; g++)
            bs[ct][g] = biasP[cg*64 + ct*16 + g*4 + um];

    // DMA source per-lane offsets (f16 units). Chunk c: row = c*16 + (l>>2),
    // source granule swizzle ((l&3)^((l>>2)&3))*8.
    const int swz = ((l & 3) ^ ((l >> 2) & 3))*8;
    const int rl4 = l >> 2;
    const int srcH0 = (bg*64 +  0 + rl4)*HID + swz;
    const int srcH1 = (bg*64 + 16 + rl4)*HID + swz;
    const int srcH2 = (bg*64 + 32 + rl4)*HID + swz;
    const int srcH3 = (bg*64 + 48 + rl4)*HID + swz;
    const int srcX0 = (bg*64 +  0 + rl4)*XPAD + swz;
    const int srcX1 = (bg*64 + 16 + rl4)*XPAD + swz;
    const int srcX2 = (bg*64 + 32 + rl4)*XPAD + swz;
    const int srcX3 = (bg*64 + 48 + rl4)*XPAD + swz;

    // ds_read offsets: row = ((w+q)&3)*16 + lr; granule = lhi ^ (row&3) = lhi ^ (lr&3)
    const int gsw = (lhi ^ (lr & 3)) << 3;
    const int ofsA0 = (((w + 0) & 3)*16 + lr)*32 + gsw;
    const int ofsA1 = (((w + 1) & 3)*16 + lr)*32 + gsw;
    const int ofsA2 = (((w + 2) & 3)*16 + lr)*32 + gsw;
    const int ofsA3 = (((w + 3) & 3)*16 + lr)*32 + gsw;

    const int myrow0 = bg*64 + w*16 + lhi*4;      // kept rowtile = global rt w
    const int colW = cg*16 + gs*4 + um;           // H-store column

    float Cr[4][4];                      // [ct][r], gs-redundant
    #pragma unroll
    for (int ct = 0; ct < 4; ct++)
        #pragma unroll
        for (int r = 0; r < 4; r++)
            Cr[ct][r] = C0[(size_t)(myrow0 + r)*HID + cg*16 + ct*4 + um];

    __syncthreads();

    for (int t = 0; t < STEPS; t++){
        const f16* Hrd = (t & 1) ? Hb : Ha;
        f16*       Hwr = (t & 1) ? Ha : Hb;
        const f16* Xrow = Xbuf + (size_t)t*BATCHN*XPAD;

        // ---- drop stale cached H lines (L1+L2) before this step's plain DMAs.
        //      Per-wave acquire fence at agent scope -> buffer_inv; post-inv
        //      misses refill from LLC (fresh: H publishes are sc1 write-through).
        __builtin_amdgcn_fence(__ATOMIC_ACQUIRE, "agent");
        __builtin_amdgcn_sched_barrier(0);

        f32x4 acc[4][4];
        #pragma unroll
        for (int q = 0; q < 4; q++)
            #pragma unroll
            for (int ct = 0; ct < 4; ct++) acc[q][ct] = (f32x4){0.f,0.f,0.f,0.f};

        // ---- A staging + MFMA: 3-deep async DMA kt-ring (wave-private slots) ----
        ISSUE_DMA(0, 0);
        ISSUE_DMA(1, 1);
        #pragma unroll
        for (int kt = 0; kt < 9; kt++){
            const int slot = kt % 3;
            if (kt < 7) ISSUE_DMA(kt + 2, (kt + 2) % 3);
            WAITV(kt);
            f16x8 Af[4];
            LOADA(slot, Af);
            MM(kt, Af);
        }

        // ---- all Alds reads done before red overlay writes ----
        __syncthreads();

        // ---- cross-wave K reduction in 3 owner-phases (red overlays Alds) ----
        #pragma unroll
        for (int p = 1; p <= 3; p++){
            int o = (w + p) & 3;
            #pragma unroll
            for (int ct = 0; ct < 4; ct++)
                red[(o*4 + ct)*64 + l] = acc[p][ct];
            __syncthreads();
            #pragma unroll
            for (int ct = 0; ct < 4; ct++)
                acc[0][ct] += red[(w*4 + ct)*64 + l];
            if (p < 3) __syncthreads();
        }

        // ---- epilogue: gather gates (xor 4/8/12), update C, compute h ----
        float hall[4][4];
        #pragma unroll
        for (int ct = 0; ct < 4; ct++){
            #pragma unroll
            for (int r = 0; r < 4; r++){
                float a0 = acc[0][ct][r];
                float a1 = __shfl_xor(a0, 4, 64);
                float a2 = __shfl_xor(a0, 8, 64);
                float a3 = __shfl_xor(a0, 12, 64);
                float gi = pick4(a0,a1,a2,a3, gs    ) + bs[ct][0];
                float gf = pick4(a0,a1,a2,a3, gs ^ 1) + bs[ct][1];
                float go = pick4(a0,a1,a2,a3, gs ^ 2) + bs[ct][2];
                float gc = pick4(a0,a1,a2,a3, gs ^ 3) + bs[ct][3];
                float I = sigm(gi), F = sigm(gf), O = sigm(go), G = tanh_f(gc);
                float c = F*Cr[ct][r] + I*G;
                Cr[ct][r] = c;
                hall[ct][r] = O*tanh_f(c);
            }
        }

        // ---- H store: lane gs stores ct=gs -> each (unit,row) exactly once.
        //      Device scope (sc1 write-through to LLC = authoritative copy). ----
        #pragma unroll
        for (int r = 0; r < 4; r++){
            float hv = pick4(hall[0][r], hall[1][r], hall[2][r], hall[3][r], gs);
            f16 h16 = (f16)hv;
            f16* p = Hwr + (size_t)(myrow0 + r)*HID + colW;
            __hip_atomic_store(p, h16, __ATOMIC_RELAXED, __HIP_MEMORY_SCOPE_AGENT);
        }
        asm volatile("s_waitcnt vmcnt(0)" ::: "memory");
        __syncthreads();

        // ---- grid barrier: per-block flag (device scope), coalesced poll ----
        if (tid == 0)
            __hip_atomic_store(&flags[bid], (unsigned)(t+1), __ATOMIC_RELAXED, __HIP_MEMORY_SCOPE_AGENT);
        if (w == 0){
            unsigned tgt = (unsigned)(t+1), guard = 0;
            for (;;){
                unsigned f0 = __hip_atomic_load(&flags[l      ], __ATOMIC_RELAXED, __HIP_MEMORY_SCOPE_AGENT);
                unsigned f1 = __hip_atomic_load(&flags[l +  64], __ATOMIC_RELAXED, __HIP_MEMORY_SCOPE_AGENT);
                unsigned f2 = __hip_atomic_load(&flags[l + 128], __ATOMIC_RELAXED, __HIP_MEMORY_SCOPE_AGENT);
                unsigned f3 = __hip_atomic_load(&flags[l + 192], __ATOMIC_RELAXED, __HIP_MEMORY_SCOPE_AGENT);
                bool ok = (f0 >= tgt) && (f1 >= tgt) && (f2 >= tgt) && (f3 >= tgt);
                if (__all(ok)) break;
                if (++guard > 2000000u){ s_bail = 1; break; }
                __builtin_amdgcn_s_sleep(1);
            }
        }
        __syncthreads();
        if (s_bail) break;
    }

    // ---- final dense: H(final, in Ha) @ dense_w + dense_b -> out[256][2] ----
    if (cg == 0){
        int r = tid >> 2, j = (tid >> 1) & 1, half = tid & 1;
        int row = bg*64 + r;
        const f16* hrow = Ha + (size_t)row*HID + half*512;
        float s = 0.f;
        for (int v = 0; v < 64; v++){
            f16x8 h8;
            asm volatile("global_load_dwordx4 %0, %1, off sc1" : "=v"(h8) : "v"(hrow + v*8));
            asm volatile("s_waitcnt vmcnt(0)" ::: "memory");
            #pragma unroll
            for (int e = 0; e < 8; e++)
                s += (float)h8[e] * dw[(size_t)(half*512 + v*8 + e)*2 + j];
        }
        s += __shfl_xor(s, 1, 64);
        if (half == 0) out[(size_t)row*2 + j] = s + db[j];
    }
}

extern "C" void kernel_launch(void* const* d_in, const int* in_sizes, int n_in,
                              void* d_out, int out_size, void* d_ws, size_t ws_size,
                              hipStream_t stream)
{
    const int*   tokens = (const int*)d_in[0];
    const float* H0  = (const float*)d_in[1];
    const float* C0  = (const float*)d_in[2];
    const float* Wxi = (const float*)d_in[3];
    const float* Whi = (const float*)d_in[4];
    const float* bi  = (const float*)d_in[5];
    const float* Wxf = (const float*)d_in[6];
    const float* Whf = (const float*)d_in[7];
    const float* bf  = (const float*)d_in[8];
    const float* Wxo = (const float*)d_in[9];
    const float* Who = (const float*)d_in[10];
    const float* bo  = (const float*)d_in[11];
    const float* Wxc = (const float*)d_in[12];
    const float* Whc = (const float*)d_in[13];
    const float* bc  = (const float*)d_in[14];
    const float* emb = (const float*)d_in[15];
    const float* dw  = (const float*)d_in[16];
    const float* db  = (const float*)d_in[17];
    float* out = (float*)d_out;

    char* ws = (char*)d_ws;
    size_t off = 0;
    auto alloc = [&](size_t bytes){ void* p = ws + off; off += (bytes + 255) & ~(size_t)255; return p; };
    f16* WThi = (f16*)alloc((size_t)4096*KTOT*2);
    f16* WTlo = (f16*)alloc((size_t)4096*KTOT*2);
    f16* Xbuf = (f16*)alloc((size_t)STEPS*BATCHN*XPAD*2);
    f16* Ha   = (f16*)alloc((size_t)BATCHN*HID*2);
    f16* Hb   = (f16*)alloc((size_t)BATCHN*HID*2);
    float* biasP = (float*)alloc(4096*sizeof(float));
    unsigned* flags = (unsigned*)alloc(NBLK*sizeof(unsigned));
    if (off > ws_size) return;   // workspace too small: fail loud

    hipMemsetAsync(flags, 0, NBLK*sizeof(unsigned), stream);
    pack_w<<<4096, 256, 0, stream>>>(Whi,Whf,Who,Whc, Wxi,Wxf,Wxo,Wxc, bi,bf,bo,bc,
                                     WThi, WTlo, biasP);
    pack_x<<<STEPS*BATCHN, 128, 0, stream>>>(tokens, emb, Xbuf);
    pack_h0<<<(BATCHN*HID + 255)/256, 256, 0, stream>>>(H0, Ha);
    lstm_main<<<NBLK, 256, 0, stream>>>(WThi, WTlo, Xbuf, biasP, C0, Ha, Hb,
                                        dw, db, out, flags);
}

// Round 11
// 7080.471 us; speedup vs baseline: 1.4990x; 1.4990x over previous
//
#include <hip/hip_runtime.h>

typedef _Float16 f16;
typedef _Float16 f16x8 __attribute__((ext_vector_type(8)));
typedef float f32x4 __attribute__((ext_vector_type(4)));

#define STEPS 512
#define BATCHN 256
#define HID 1024
#define EMBN 100
#define KTOT 1152
#define XPAD 128
#define NBLK 256

__device__ __forceinline__ float sigm(float x){ return 1.f/(1.f+__expf(-x)); }
__device__ __forceinline__ float tanh_f(float x){
    float e = __expf(2.f*fabsf(x));
    float r = 1.f - 2.f/(e+1.f);
    return x >= 0.f ? r : -r;
}
// select {a0,a1,a2,a3}[idx] without runtime-indexed array (rule #20)
__device__ __forceinline__ float pick4(float a0, float a1, float a2, float a3, int idx){
    float t0 = (idx & 1) ? a1 : a0;
    float t1 = (idx & 1) ? a3 : a2;
    return (idx & 2) ? t1 : t0;
}

// Pack W_h(1024 rows)+W_x(100)+pad -> WT[4096][1152] f16 (hi only).
// Col J = cg*64 + ct*16 + g*4 + um -> unit u = cg*16 + ct*4 + um. Also bias[J].
__global__ void pack_w(const float* __restrict__ Whi_, const float* __restrict__ Whf_,
                       const float* __restrict__ Who_, const float* __restrict__ Whc_,
                       const float* __restrict__ Wxi_, const float* __restrict__ Wxf_,
                       const float* __restrict__ Wxo_, const float* __restrict__ Wxc_,
                       const float* __restrict__ bi_, const float* __restrict__ bf_,
                       const float* __restrict__ bo_, const float* __restrict__ bc_,
                       f16* __restrict__ WThi, float* __restrict__ biasP)
{
    int J = blockIdx.x;                 // 0..4095
    int cg = J >> 6, ct = (J >> 4) & 3, g = (J >> 2) & 3, um = J & 3;
    int u = cg*16 + ct*4 + um;
    const float* Wh = (g==0)?Whi_:(g==1)?Whf_:(g==2)?Who_:Whc_;
    const float* Wx = (g==0)?Wxi_:(g==1)?Wxf_:(g==2)?Wxo_:Wxc_;
    for (int k = threadIdx.x; k < KTOT; k += blockDim.x){
        float v = 0.f;
        if (k < 1024)       v = Wh[(size_t)k*HID + u];
        else if (k < 1124)  v = Wx[(size_t)(k-1024)*HID + u];
        WThi[(size_t)J*KTOT + k] = (f16)v;
    }
    if (threadIdx.x == 0){
        const float* bb = (g==0)?bi_:(g==1)?bf_:(g==2)?bo_:bc_;
        biasP[J] = bb[u];
    }
}

__global__ void pack_x(const int* __restrict__ tokens, const float* __restrict__ emb,
                       f16* __restrict__ Xbuf)
{
    int bid = blockIdx.x;               // t*256 + row
    int t = bid >> 8, row = bid & 255;
    int tok = tokens[(size_t)row*STEPS + t];
    int kx = threadIdx.x;               // 0..127
    float v = (kx < EMBN) ? emb[(size_t)tok*EMBN + kx] : 0.f;
    Xbuf[(size_t)bid*XPAD + kx] = (f16)v;
}

__global__ void pack_h0(const float* __restrict__ H0, f16* __restrict__ Hb)
{
    int i = blockIdx.x*blockDim.x + threadIdx.x;
    if (i < BATCHN*HID) Hb[i] = (f16)H0[i];
}

// One k-tile's A fragments -> 4 register loads (round-4 proven addressing).
// H rows: device-scope sc1 (LLC). X rows: plain cached (immutable).
#define ISSUE(kt_, AF) do {                                                              \
    const int kb_ = w*288 + (kt_)*32;                                                    \
    if (kb_ < 1024) {                                                                    \
        const f16* hb_ = Hrd + kb_ + lhi*8;                                              \
        asm volatile("global_load_dwordx4 %0, %1, off sc1" : "=v"(AF[0]) : "v"(hb_ + (size_t)rA[0]*HID)); \
        asm volatile("global_load_dwordx4 %0, %1, off sc1" : "=v"(AF[1]) : "v"(hb_ + (size_t)rA[1]*HID)); \
        asm volatile("global_load_dwordx4 %0, %1, off sc1" : "=v"(AF[2]) : "v"(hb_ + (size_t)rA[2]*HID)); \
        asm volatile("global_load_dwordx4 %0, %1, off sc1" : "=v"(AF[3]) : "v"(hb_ + (size_t)rA[3]*HID)); \
    } else {                                                                             \
        const f16* xb_ = Xrow + (kb_ - 1024) + lhi*8;                                    \
        asm volatile("global_load_dwordx4 %0, %1, off" : "=v"(AF[0]) : "v"(xb_ + (size_t)rA[0]*XPAD)); \
        asm volatile("global_load_dwordx4 %0, %1, off" : "=v"(AF[1]) : "v"(xb_ + (size_t)rA[1]*XPAD)); \
        asm volatile("global_load_dwordx4 %0, %1, off" : "=v"(AF[2]) : "v"(xb_ + (size_t)rA[2]*XPAD)); \
        asm volatile("global_load_dwordx4 %0, %1, off" : "=v"(AF[3]) : "v"(xb_ + (size_t)rA[3]*XPAD)); \
    }                                                                                    \
} while(0)

#define WAITN(n_) do {                                                                   \
    asm volatile("s_waitcnt vmcnt(" #n_ ")" ::: "memory");                               \
    __builtin_amdgcn_sched_barrier(0);                                                   \
} while(0)

// Hi-only MFMA: 16 per k-tile (half of the hi/lo version).
#define MM(kt_, AF) do {                                                                 \
    _Pragma("unroll")                                                                    \
    for (int q_ = 0; q_ < 4; q_++){                                                      \
        _Pragma("unroll")                                                                \
        for (int ct_ = 0; ct_ < 4; ct_++){                                               \
            acc[q_][ct_] = __builtin_amdgcn_mfma_f32_16x16x32_f16(AF[q_], Bf[kt_][ct_], acc[q_][ct_], 0,0,0); \
        }                                                                                \
    }                                                                                    \
} while(0)

// Persistent LSTM: 256 blocks (4 bg x 64 cg) x 256 threads, 1/CU.
// Weights f16 HI-ONLY in AGPR (144/lane; numerics experiment — round 3's
// "hi-only insufficient" was a launch failure, never a numerics result).
// A loaded via 36-deep pure-register pipeline: all 9 k-tiles issued up front
// (9 buffers x 4 loads), descending vmcnt(32..0). No LDS staging. H + flags
// at device scope (sc1/LLC). Round-4 reduction/epilogue/barrier verbatim.
__global__ __launch_bounds__(256, 1) void lstm_main(
    const f16* __restrict__ WThi, const f16* __restrict__ Xbuf,
    const float* __restrict__ biasP, const float* __restrict__ C0,
    f16* __restrict__ Ha, f16* __restrict__ Hb,
    const float* __restrict__ dw, const float* __restrict__ db,
    float* __restrict__ out, unsigned* __restrict__ flags)
{
    __shared__ f32x4 red[4*3*4*64];     // [owner][q1][ct][lane], 48KB
    __shared__ int s_bail;

    const int bid = blockIdx.x;
    const int bg = bid & 3, cg = bid >> 2;
    const int tid = threadIdx.x;
    const int w = tid >> 6, l = tid & 63, lr = l & 15, lhi = l >> 4;
    const int um = l & 3, gs = lr >> 2;
    if (tid == 0) s_bail = 0;

    // ---- persistent weights: 9 kt x 4 ct = 144 regs/lane (AGPR-resident) ----
    f16x8 Bf[9][4];
    #pragma unroll
    for (int kt = 0; kt < 9; kt++){
        int k0 = w*288 + kt*32 + lhi*8;
        #pragma unroll
        for (int ct = 0; ct < 4; ct++)
            Bf[kt][ct] = *(const f16x8*)(WThi + (size_t)(cg*64 + ct*16 + lr)*KTOT + k0);
    }
    float bs[4][4];                      // [ct][gate]
    #pragma unroll
    for (int ct = 0; ct < 4; ct++)
        #pragma unroll
        for (int g = 0; g < 4; g++)
            bs[ct][g] = biasP[cg*64 + ct*16 + g*4 + um];

    int rA[4];
    #pragma unroll
    for (int q = 0; q < 4; q++) rA[q] = bg*64 + ((w + q) & 3)*16 + lr;
    const int myrow0 = bg*64 + w*16 + lhi*4;      // kept rowtile = global rt w
    const int colW = cg*16 + gs*4 + um;           // H-store column

    float Cr[4][4];                      // [ct][r], gs-redundant
    #pragma unroll
    for (int ct = 0; ct < 4; ct++)
        #pragma unroll
        for (int r = 0; r < 4; r++)
            Cr[ct][r] = C0[(size_t)(myrow0 + r)*HID + cg*16 + ct*4 + um];

    __syncthreads();

    for (int t = 0; t < STEPS; t++){
        const f16* Hrd = (t & 1) ? Hb : Ha;
        f16*       Hwr = (t & 1) ? Ha : Hb;
        const f16* Xrow = Xbuf + (size_t)t*BATCHN*XPAD;

        f32x4 acc[4][4];
        #pragma unroll
        for (int q = 0; q < 4; q++)
            #pragma unroll
            for (int ct = 0; ct < 4; ct++) acc[q][ct] = (f32x4){0.f,0.f,0.f,0.f};

        // ---- 36-deep pure-register A pipeline: all 9 k-tiles in flight ----
        f16x8 A0[4], A1[4], A2[4], A3[4], A4[4], A5[4], A6[4], A7[4], A8[4];
        ISSUE(0, A0); ISSUE(1, A1); ISSUE(2, A2); ISSUE(3, A3); ISSUE(4, A4);
        ISSUE(5, A5); ISSUE(6, A6); ISSUE(7, A7); ISSUE(8, A8);

        WAITN(32); MM(0, A0);
        WAITN(28); MM(1, A1);
        WAITN(24); MM(2, A2);
        WAITN(20); MM(3, A3);
        WAITN(16); MM(4, A4);
        WAITN(12); MM(5, A5);
        WAITN(8);  MM(6, A6);
        WAITN(4);  MM(7, A7);
        WAITN(0);  MM(8, A8);

        // ---- cross-wave K reduction (kept tile q=0 <-> global rt w) ----
        #pragma unroll
        for (int q = 1; q < 4; q++){
            int o = (w + q) & 3;
            #pragma unroll
            for (int ct = 0; ct < 4; ct++)
                red[((o*3 + (q-1))*4 + ct)*64 + l] = acc[q][ct];
        }
        __syncthreads();
        #pragma unroll
        for (int q1 = 0; q1 < 3; q1++)
            #pragma unroll
            for (int ct = 0; ct < 4; ct++)
                acc[0][ct] += red[((w*3 + q1)*4 + ct)*64 + l];

        // ---- epilogue: gather gates (xor 4/8/12), update C, compute h ----
        float hall[4][4];
        #pragma unroll
        for (int ct = 0; ct < 4; ct++){
            #pragma unroll
            for (int r = 0; r < 4; r++){
                float a0 = acc[0][ct][r];
                float a1 = __shfl_xor(a0, 4, 64);
                float a2 = __shfl_xor(a0, 8, 64);
                float a3 = __shfl_xor(a0, 12, 64);
                float gi = pick4(a0,a1,a2,a3, gs    ) + bs[ct][0];
                float gf = pick4(a0,a1,a2,a3, gs ^ 1) + bs[ct][1];
                float go = pick4(a0,a1,a2,a3, gs ^ 2) + bs[ct][2];
                float gc = pick4(a0,a1,a2,a3, gs ^ 3) + bs[ct][3];
                float I = sigm(gi), F = sigm(gf), O = sigm(go), G = tanh_f(gc);
                float c = F*Cr[ct][r] + I*G;
                Cr[ct][r] = c;
                hall[ct][r] = O*tanh_f(c);
            }
        }

        // ---- H store: lane gs stores ct=gs -> each (unit,row) exactly once.
        //      Device scope (sc1 write-through to LLC). ----
        #pragma unroll
        for (int r = 0; r < 4; r++){
            float hv = pick4(hall[0][r], hall[1][r], hall[2][r], hall[3][r], gs);
            f16 h16 = (f16)hv;
            f16* p = Hwr + (size_t)(myrow0 + r)*HID + colW;
            __hip_atomic_store(p, h16, __ATOMIC_RELAXED, __HIP_MEMORY_SCOPE_AGENT);
        }
        asm volatile("s_waitcnt vmcnt(0)" ::: "memory");
        __syncthreads();

        // ---- grid barrier: per-block flag (device scope), coalesced poll ----
        if (tid == 0)
            __hip_atomic_store(&flags[bid], (unsigned)(t+1), __ATOMIC_RELAXED, __HIP_MEMORY_SCOPE_AGENT);
        if (w == 0){
            unsigned tgt = (unsigned)(t+1), guard = 0;
            for (;;){
                unsigned f0 = __hip_atomic_load(&flags[l      ], __ATOMIC_RELAXED, __HIP_MEMORY_SCOPE_AGENT);
                unsigned f1 = __hip_atomic_load(&flags[l +  64], __ATOMIC_RELAXED, __HIP_MEMORY_SCOPE_AGENT);
                unsigned f2 = __hip_atomic_load(&flags[l + 128], __ATOMIC_RELAXED, __HIP_MEMORY_SCOPE_AGENT);
                unsigned f3 = __hip_atomic_load(&flags[l + 192], __ATOMIC_RELAXED, __HIP_MEMORY_SCOPE_AGENT);
                bool ok = (f0 >= tgt) && (f1 >= tgt) && (f2 >= tgt) && (f3 >= tgt);
                if (__all(ok)) break;
                if (++guard > 2000000u){ s_bail = 1; break; }
                __builtin_amdgcn_s_sleep(1);
            }
        }
        __syncthreads();
        if (s_bail) break;
    }

    // ---- final dense: H(final, in Ha) @ dense_w + dense_b -> out[256][2] ----
    if (cg == 0){
        int r = tid >> 2, j = (tid >> 1) & 1, half = tid & 1;
        int row = bg*64 + r;
        const f16* hrow = Ha + (size_t)row*HID + half*512;
        float s = 0.f;
        for (int v = 0; v < 64; v++){
            f16x8 h8;
            asm volatile("global_load_dwordx4 %0, %1, off sc1" : "=v"(h8) : "v"(hrow + v*8));
            asm volatile("s_waitcnt vmcnt(0)" ::: "memory");
            #pragma unroll
            for (int e = 0; e < 8; e++)
                s += (float)h8[e] * dw[(size_t)(half*512 + v*8 + e)*2 + j];
        }
        s += __shfl_xor(s, 1, 64);
        if (half == 0) out[(size_t)row*2 + j] = s + db[j];
    }
}

extern "C" void kernel_launch(void* const* d_in, const int* in_sizes, int n_in,
                              void* d_out, int out_size, void* d_ws, size_t ws_size,
                              hipStream_t stream)
{
    const int*   tokens = (const int*)d_in[0];
    const float* H0  = (const float*)d_in[1];
    const float* C0  = (const float*)d_in[2];
    const float* Wxi = (const float*)d_in[3];
    const float* Whi = (const float*)d_in[4];
    const float* bi  = (const float*)d_in[5];
    const float* Wxf = (const float*)d_in[6];
    const float* Whf = (const float*)d_in[7];
    const float* bf  = (const float*)d_in[8];
    const float* Wxo = (const float*)d_in[9];
    const float* Who = (const float*)d_in[10];
    const float* bo  = (const float*)d_in[11];
    const float* Wxc = (const float*)d_in[12];
    const float* Whc = (const float*)d_in[13];
    const float* bc  = (const float*)d_in[14];
    const float* emb = (const float*)d_in[15];
    const float* dw  = (const float*)d_in[16];
    const float* db  = (const float*)d_in[17];
    float* out = (float*)d_out;

    char* ws = (char*)d_ws;
    size_t off = 0;
    auto alloc = [&](size_t bytes){ void* p = ws + off; off += (bytes + 255) & ~(size_t)255; return p; };
    f16* WThi = (f16*)alloc((size_t)4096*KTOT*2);
    f16* Xbuf = (f16*)alloc((size_t)STEPS*BATCHN*XPAD*2);
    f16* Ha   = (f16*)alloc((size_t)BATCHN*HID*2);
    f16* Hb   = (f16*)alloc((size_t)BATCHN*HID*2);
    float* biasP = (float*)alloc(4096*sizeof(float));
    unsigned* flags = (unsigned*)alloc(NBLK*sizeof(unsigned));
    if (off > ws_size) return;   // workspace too small: fail loud

    hipMemsetAsync(flags, 0, NBLK*sizeof(unsigned), stream);
    pack_w<<<4096, 256, 0, stream>>>(Whi,Whf,Who,Whc, Wxi,Wxf,Wxo,Wxc, bi,bf,bo,bc,
                                     WThi, biasP);
    pack_x<<<STEPS*BATCHN, 128, 0, stream>>>(tokens, emb, Xbuf);
    pack_h0<<<(BATCHN*HID + 255)/256, 256, 0, stream>>>(H0, Ha);
    lstm_main<<<NBLK, 256, 0, stream>>>(WThi, Xbuf, biasP, C0, Ha, Hb,
                                        dw, db, out, flags);
}

// Round 12
// 6866.862 us; speedup vs baseline: 1.5456x; 1.0311x over previous
//
#include <hip/hip_runtime.h>

typedef _Float16 f16;
typedef _Float16 f16x8 __attribute__((ext_vector_type(8)));
typedef float f32x4 __attribute__((ext_vector_type(4)));

#define STEPS 512
#define BATCHN 256
#define HID 1024
#define EMBN 100
#define KTOT 1152
#define XPAD 128
#define NBLK 256
#define HSLOT ((size_t)BATCHN*HID)     // f16 elems per H snapshot (512KB)

__device__ __forceinline__ float sigm(float x){ return 1.f/(1.f+__expf(-x)); }
__device__ __forceinline__ float tanh_f(float x){
    float e = __expf(2.f*fabsf(x));
    float r = 1.f - 2.f/(e+1.f);
    return x >= 0.f ? r : -r;
}
// select {a0,a1,a2,a3}[idx] without runtime-indexed array (rule #20)
__device__ __forceinline__ float pick4(float a0, float a1, float a2, float a3, int idx){
    float t0 = (idx & 1) ? a1 : a0;
    float t1 = (idx & 1) ? a3 : a2;
    return (idx & 2) ? t1 : t0;
}

// Pack W_h(1024 rows)+W_x(100)+pad -> WT[4096][1152] f16 (hi only; validated
// round 11: absmax 1.22e-4). Col J = cg*64+ct*16+g*4+um -> unit u. Also bias[J].
__global__ void pack_w(const float* __restrict__ Whi_, const float* __restrict__ Whf_,
                       const float* __restrict__ Who_, const float* __restrict__ Whc_,
                       const float* __restrict__ Wxi_, const float* __restrict__ Wxf_,
                       const float* __restrict__ Wxo_, const float* __restrict__ Wxc_,
                       const float* __restrict__ bi_, const float* __restrict__ bf_,
                       const float* __restrict__ bo_, const float* __restrict__ bc_,
                       f16* __restrict__ WThi, float* __restrict__ biasP)
{
    int J = blockIdx.x;                 // 0..4095
    int cg = J >> 6, ct = (J >> 4) & 3, g = (J >> 2) & 3, um = J & 3;
    int u = cg*16 + ct*4 + um;
    const float* Wh = (g==0)?Whi_:(g==1)?Whf_:(g==2)?Who_:Whc_;
    const float* Wx = (g==0)?Wxi_:(g==1)?Wxf_:(g==2)?Wxo_:Wxc_;
    for (int k = threadIdx.x; k < KTOT; k += blockDim.x){
        float v = 0.f;
        if (k < 1024)       v = Wh[(size_t)k*HID + u];
        else if (k < 1124)  v = Wx[(size_t)(k-1024)*HID + u];
        WThi[(size_t)J*KTOT + k] = (f16)v;
    }
    if (threadIdx.x == 0){
        const float* bb = (g==0)?bi_:(g==1)?bf_:(g==2)?bo_:bc_;
        biasP[J] = bb[u];
    }
}

__global__ void pack_x(const int* __restrict__ tokens, const float* __restrict__ emb,
                       f16* __restrict__ Xbuf)
{
    int bid = blockIdx.x;               // t*256 + row
    int t = bid >> 8, row = bid & 255;
    int tok = tokens[(size_t)row*STEPS + t];
    int kx = threadIdx.x;               // 0..127
    float v = (kx < EMBN) ? emb[(size_t)tok*EMBN + kx] : 0.f;
    Xbuf[(size_t)bid*XPAD + kx] = (f16)v;
}

__global__ void pack_h0(const float* __restrict__ H0, f16* __restrict__ Hb)
{
    int i = blockIdx.x*blockDim.x + threadIdx.x;
    if (i < BATCHN*HID) Hb[i] = (f16)H0[i];
}

// One k-tile's A fragments -> 4 register loads.
// hist mode: H PLAIN-cached (fresh-address-per-step makes staleness impossible;
// XCD L2 broadcasts to the 32 blocks sharing this bg). fallback: sc1 (round 11).
// X rows always plain (immutable). Both arms issue exactly 4 VMEM ops, so the
// hand-counted vmcnt schedule is branch-invariant.
#define ISSUE(kt_, AF) do {                                                              \
    const int kb_ = w*288 + (kt_)*32;                                                    \
    if (kb_ < 1024) {                                                                    \
        const f16* hb_ = Hrd + kb_ + lhi*8;                                              \
        if (hist) {                                                                      \
            asm volatile("global_load_dwordx4 %0, %1, off" : "=v"(AF[0]) : "v"(hb_ + (size_t)rA[0]*HID)); \
            asm volatile("global_load_dwordx4 %0, %1, off" : "=v"(AF[1]) : "v"(hb_ + (size_t)rA[1]*HID)); \
            asm volatile("global_load_dwordx4 %0, %1, off" : "=v"(AF[2]) : "v"(hb_ + (size_t)rA[2]*HID)); \
            asm volatile("global_load_dwordx4 %0, %1, off" : "=v"(AF[3]) : "v"(hb_ + (size_t)rA[3]*HID)); \
        } else {                                                                         \
            asm volatile("global_load_dwordx4 %0, %1, off sc1" : "=v"(AF[0]) : "v"(hb_ + (size_t)rA[0]*HID)); \
            asm volatile("global_load_dwordx4 %0, %1, off sc1" : "=v"(AF[1]) : "v"(hb_ + (size_t)rA[1]*HID)); \
            asm volatile("global_load_dwordx4 %0, %1, off sc1" : "=v"(AF[2]) : "v"(hb_ + (size_t)rA[2]*HID)); \
            asm volatile("global_load_dwordx4 %0, %1, off sc1" : "=v"(AF[3]) : "v"(hb_ + (size_t)rA[3]*HID)); \
        }                                                                                \
    } else {                                                                             \
        const f16* xb_ = Xrow + (kb_ - 1024) + lhi*8;                                    \
        asm volatile("global_load_dwordx4 %0, %1, off" : "=v"(AF[0]) : "v"(xb_ + (size_t)rA[0]*XPAD)); \
        asm volatile("global_load_dwordx4 %0, %1, off" : "=v"(AF[1]) : "v"(xb_ + (size_t)rA[1]*XPAD)); \
        asm volatile("global_load_dwordx4 %0, %1, off" : "=v"(AF[2]) : "v"(xb_ + (size_t)rA[2]*XPAD)); \
        asm volatile("global_load_dwordx4 %0, %1, off" : "=v"(AF[3]) : "v"(xb_ + (size_t)rA[3]*XPAD)); \
    }                                                                                    \
} while(0)

#define WAITN(n_) do {                                                                   \
    asm volatile("s_waitcnt vmcnt(" #n_ ")" ::: "memory");                               \
    __builtin_amdgcn_sched_barrier(0);                                                   \
} while(0)

// Hi-only MFMA: 16 per k-tile.
#define MM(kt_, AF) do {                                                                 \
    _Pragma("unroll")                                                                    \
    for (int q_ = 0; q_ < 4; q_++){                                                      \
        _Pragma("unroll")                                                                \
        for (int ct_ = 0; ct_ < 4; ct_++){                                               \
            acc[q_][ct_] = __builtin_amdgcn_mfma_f32_16x16x32_f16(AF[q_], Bf[kt_][ct_], acc[q_][ct_], 0,0,0); \
        }                                                                                \
    }                                                                                    \
} while(0)

// Persistent LSTM: 256 blocks (4 bg x 64 cg) x 256 threads, 1/CU.
// Weights f16 hi-only in AGPR (144/lane). H exchange: per-step FRESH buffer
// (hist mode) -> plain cached reads, XCD-L2 broadcast, no fences; fallback
// ping-pong + sc1 if workspace too small. Publishes sc1 (LLC authoritative).
__global__ __launch_bounds__(256, 1) void lstm_main(
    const f16* __restrict__ WThi, const f16* __restrict__ Xbuf,
    const float* __restrict__ biasP, const float* __restrict__ C0,
    f16* __restrict__ H, int hist,
    const float* __restrict__ dw, const float* __restrict__ db,
    float* __restrict__ out, unsigned* __restrict__ flags)
{
    __shared__ f32x4 red[4*3*4*64];     // [owner][q1][ct][lane], 48KB
    __shared__ int s_bail;

    const int bid = blockIdx.x;
    const int bg = bid & 3, cg = bid >> 2;
    const int tid = threadIdx.x;
    const int w = tid >> 6, l = tid & 63, lr = l & 15, lhi = l >> 4;
    const int um = l & 3, gs = lr >> 2;
    if (tid == 0) s_bail = 0;

    // ---- persistent weights: 9 kt x 4 ct = 144 regs/lane (AGPR-resident) ----
    f16x8 Bf[9][4];
    #pragma unroll
    for (int kt = 0; kt < 9; kt++){
        int k0 = w*288 + kt*32 + lhi*8;
        #pragma unroll
        for (int ct = 0; ct < 4; ct++)
            Bf[kt][ct] = *(const f16x8*)(WThi + (size_t)(cg*64 + ct*16 + lr)*KTOT + k0);
    }
    float bs[4][4];                      // [ct][gate]
    #pragma unroll
    for (int ct = 0; ct < 4; ct++)
        #pragma unroll
        for (int g = 0; g < 4; g++)
            bs[ct][g] = biasP[cg*64 + ct*16 + g*4 + um];

    int rA[4];
    #pragma unroll
    for (int q = 0; q < 4; q++) rA[q] = bg*64 + ((w + q) & 3)*16 + lr;
    const int myrow0 = bg*64 + w*16 + lhi*4;      // kept rowtile = global rt w
    const int colW = cg*16 + gs*4 + um;           // H-store column

    float Cr[4][4];                      // [ct][r], gs-redundant
    #pragma unroll
    for (int ct = 0; ct < 4; ct++)
        #pragma unroll
        for (int r = 0; r < 4; r++)
            Cr[ct][r] = C0[(size_t)(myrow0 + r)*HID + cg*16 + ct*4 + um];

    __syncthreads();

    for (int t = 0; t < STEPS; t++){
        const f16* Hrd = H + (size_t)(hist ? t       : (t & 1)      )*HSLOT;
        f16*       Hwr = H + (size_t)(hist ? (t + 1) : ((t + 1) & 1))*HSLOT;
        const f16* Xrow = Xbuf + (size_t)t*BATCHN*XPAD;

        f32x4 acc[4][4];
        #pragma unroll
        for (int q = 0; q < 4; q++)
            #pragma unroll
            for (int ct = 0; ct < 4; ct++) acc[q][ct] = (f32x4){0.f,0.f,0.f,0.f};

        // ---- 36-deep pure-register A pipeline: all 9 k-tiles in flight ----
        f16x8 A0[4], A1[4], A2[4], A3[4], A4[4], A5[4], A6[4], A7[4], A8[4];
        ISSUE(0, A0); ISSUE(1, A1); ISSUE(2, A2); ISSUE(3, A3); ISSUE(4, A4);
        ISSUE(5, A5); ISSUE(6, A6); ISSUE(7, A7); ISSUE(8, A8);

        WAITN(32); MM(0, A0);
        WAITN(28); MM(1, A1);
        WAITN(24); MM(2, A2);
        WAITN(20); MM(3, A3);
        WAITN(16); MM(4, A4);
        WAITN(12); MM(5, A5);
        WAITN(8);  MM(6, A6);
        WAITN(4);  MM(7, A7);
        WAITN(0);  MM(8, A8);

        // ---- cross-wave K reduction (kept tile q=0 <-> global rt w) ----
        #pragma unroll
        for (int q = 1; q < 4; q++){
            int o = (w + q) & 3;
            #pragma unroll
            for (int ct = 0; ct < 4; ct++)
                red[((o*3 + (q-1))*4 + ct)*64 + l] = acc[q][ct];
        }
        __syncthreads();
        #pragma unroll
        for (int q1 = 0; q1 < 3; q1++)
            #pragma unroll
            for (int ct = 0; ct < 4; ct++)
                acc[0][ct] += red[((w*3 + q1)*4 + ct)*64 + l];

        // ---- epilogue: gather gates (xor 4/8/12), update C, compute h ----
        float hall[4][4];
        #pragma unroll
        for (int ct = 0; ct < 4; ct++){
            #pragma unroll
            for (int r = 0; r < 4; r++){
                float a0 = acc[0][ct][r];
                float a1 = __shfl_xor(a0, 4, 64);
                float a2 = __shfl_xor(a0, 8, 64);
                float a3 = __shfl_xor(a0, 12, 64);
                float gi = pick4(a0,a1,a2,a3, gs    ) + bs[ct][0];
                float gf = pick4(a0,a1,a2,a3, gs ^ 1) + bs[ct][1];
                float go = pick4(a0,a1,a2,a3, gs ^ 2) + bs[ct][2];
                float gc = pick4(a0,a1,a2,a3, gs ^ 3) + bs[ct][3];
                float I = sigm(gi), F = sigm(gf), O = sigm(go), G = tanh_f(gc);
                float c = F*Cr[ct][r] + I*G;
                Cr[ct][r] = c;
                hall[ct][r] = O*tanh_f(c);
            }
        }

        // ---- H store: lane gs stores ct=gs -> each (unit,row) exactly once.
        //      sc1 write-through to LLC (authoritative for cold reader misses). ----
        #pragma unroll
        for (int r = 0; r < 4; r++){
            float hv = pick4(hall[0][r], hall[1][r], hall[2][r], hall[3][r], gs);
            f16 h16 = (f16)hv;
            f16* p = Hwr + (size_t)(myrow0 + r)*HID + colW;
            __hip_atomic_store(p, h16, __ATOMIC_RELAXED, __HIP_MEMORY_SCOPE_AGENT);
        }
        asm volatile("s_waitcnt vmcnt(0)" ::: "memory");
        __syncthreads();

        // ---- grid barrier: per-block flag (device scope), coalesced poll ----
        if (tid == 0)
            __hip_atomic_store(&flags[bid], (unsigned)(t+1), __ATOMIC_RELAXED, __HIP_MEMORY_SCOPE_AGENT);
        if (w == 0){
            unsigned tgt = (unsigned)(t+1), guard = 0;
            for (;;){
                unsigned f0 = __hip_atomic_load(&flags[l      ], __ATOMIC_RELAXED, __HIP_MEMORY_SCOPE_AGENT);
                unsigned f1 = __hip_atomic_load(&flags[l +  64], __ATOMIC_RELAXED, __HIP_MEMORY_SCOPE_AGENT);
                unsigned f2 = __hip_atomic_load(&flags[l + 128], __ATOMIC_RELAXED, __HIP_MEMORY_SCOPE_AGENT);
                unsigned f3 = __hip_atomic_load(&flags[l + 192], __ATOMIC_RELAXED, __HIP_MEMORY_SCOPE_AGENT);
                bool ok = (f0 >= tgt) && (f1 >= tgt) && (f2 >= tgt) && (f3 >= tgt);
                if (__all(ok)) break;
                if (++guard > 2000000u){ s_bail = 1; break; }
                __builtin_amdgcn_s_sleep(1);
            }
        }
        __syncthreads();
        if (s_bail) break;
    }

    // ---- final dense: H(final) @ dense_w + dense_b -> out[256][2] ----
    if (cg == 0){
        const f16* Hf = H + (size_t)(hist ? STEPS : 0)*HSLOT;   // t=511 wrote slot 512 / slot 0
        int r = tid >> 2, j = (tid >> 1) & 1, half = tid & 1;
        int row = bg*64 + r;
        const f16* hrow = Hf + (size_t)row*HID + half*512;
        float s = 0.f;
        for (int v = 0; v < 64; v++){
            f16x8 h8;
            asm volatile("global_load_dwordx4 %0, %1, off sc1" : "=v"(h8) : "v"(hrow + v*8));
            asm volatile("s_waitcnt vmcnt(0)" ::: "memory");
            #pragma unroll
            for (int e = 0; e < 8; e++)
                s += (float)h8[e] * dw[(size_t)(half*512 + v*8 + e)*2 + j];
        }
        s += __shfl_xor(s, 1, 64);
        if (half == 0) out[(size_t)row*2 + j] = s + db[j];
    }
}

extern "C" void kernel_launch(void* const* d_in, const int* in_sizes, int n_in,
                              void* d_out, int out_size, void* d_ws, size_t ws_size,
                              hipStream_t stream)
{
    const int*   tokens = (const int*)d_in[0];
    const float* H0  = (const float*)d_in[1];
    const float* C0  = (const float*)d_in[2];
    const float* Wxi = (const float*)d_in[3];
    const float* Whi = (const float*)d_in[4];
    const float* bi  = (const float*)d_in[5];
    const float* Wxf = (const float*)d_in[6];
    const float* Whf = (const float*)d_in[7];
    const float* bf  = (const float*)d_in[8];
    const float* Wxo = (const float*)d_in[9];
    const float* Who = (const float*)d_in[10];
    const float* bo  = (const float*)d_in[11];
    const float* Wxc = (const float*)d_in[12];
    const float* Whc = (const float*)d_in[13];
    const float* bc  = (const float*)d_in[14];
    const float* emb = (const float*)d_in[15];
    const float* dw  = (const float*)d_in[16];
    const float* db  = (const float*)d_in[17];
    float* out = (float*)d_out;

    char* ws = (char*)d_ws;
    size_t off = 0;
    auto alloc = [&](size_t bytes){ void* p = ws + off; off += (bytes + 255) & ~(size_t)255; return p; };
    f16* WThi = (f16*)alloc((size_t)4096*KTOT*2);
    f16* Xbuf = (f16*)alloc((size_t)STEPS*BATCHN*XPAD*2);
    float* biasP = (float*)alloc(4096*sizeof(float));
    unsigned* flags = (unsigned*)alloc(NBLK*sizeof(unsigned));

    // History mode: one fresh 512KB H snapshot per step (plain-cached reads,
    // XCD-L2 broadcast). Fallback: 2-slot ping-pong + sc1 (round-11 behavior).
    size_t histBytes = (size_t)(STEPS + 1)*HSLOT*2;
    int hist = (off + histBytes <= ws_size) ? 1 : 0;
    f16* H = (f16*)alloc(hist ? histBytes : 2*HSLOT*2);
    if (off > ws_size) return;   // workspace too small: fail loud

    hipMemsetAsync(flags, 0, NBLK*sizeof(unsigned), stream);
    pack_w<<<4096, 256, 0, stream>>>(Whi,Whf,Who,Whc, Wxi,Wxf,Wxo,Wxc, bi,bf,bo,bc,
                                     WThi, biasP);
    pack_x<<<STEPS*BATCHN, 128, 0, stream>>>(tokens, emb, Xbuf);
    pack_h0<<<(BATCHN*HID + 255)/256, 256, 0, stream>>>(H0, H);   // slot 0
    lstm_main<<<NBLK, 256, 0, stream>>>(WThi, Xbuf, biasP, C0, H, hist,
                                        dw, db, out, flags);
}

// Round 13
// 6809.071 us; speedup vs baseline: 1.5587x; 1.0085x over previous
//
#include <hip/hip_runtime.h>

typedef _Float16 f16;
typedef _Float16 f16x8 __attribute__((ext_vector_type(8)));
typedef float f32x4 __attribute__((ext_vector_type(4)));

#define STEPS 512
#define BATCHN 256
#define HID 1024
#define EMBN 100
#define KTOT 1152
#define XPAD 128
#define NBLK 256
#define HSLOT ((size_t)BATCHN*HID)     // f16 elems per H snapshot (512KB)

__device__ __forceinline__ float sigm(float x){ return 1.f/(1.f+__expf(-x)); }
__device__ __forceinline__ float tanh_f(float x){
    float e = __expf(2.f*fabsf(x));
    float r = 1.f - 2.f/(e+1.f);
    return x >= 0.f ? r : -r;
}
// select {a0,a1,a2,a3}[idx] without runtime-indexed array (rule #20)
__device__ __forceinline__ float pick4(float a0, float a1, float a2, float a3, int idx){
    float t0 = (idx & 1) ? a1 : a0;
    float t1 = (idx & 1) ? a3 : a2;
    return (idx & 2) ? t1 : t0;
}

// Pack W_h(1024 rows)+W_x(100)+pad -> WT[4096][1152] f16 (hi only; validated
// round 11: absmax 1.22e-4). Col J = cg*64+ct*16+g*4+um -> unit u. Also bias[J].
__global__ void pack_w(const float* __restrict__ Whi_, const float* __restrict__ Whf_,
                       const float* __restrict__ Who_, const float* __restrict__ Whc_,
                       const float* __restrict__ Wxi_, const float* __restrict__ Wxf_,
                       const float* __restrict__ Wxo_, const float* __restrict__ Wxc_,
                       const float* __restrict__ bi_, const float* __restrict__ bf_,
                       const float* __restrict__ bo_, const float* __restrict__ bc_,
                       f16* __restrict__ WThi, float* __restrict__ biasP)
{
    int J = blockIdx.x;                 // 0..4095
    int cg = J >> 6, ct = (J >> 4) & 3, g = (J >> 2) & 3, um = J & 3;
    int u = cg*16 + ct*4 + um;
    const float* Wh = (g==0)?Whi_:(g==1)?Whf_:(g==2)?Who_:Whc_;
    const float* Wx = (g==0)?Wxi_:(g==1)?Wxf_:(g==2)?Wxo_:Wxc_;
    for (int k = threadIdx.x; k < KTOT; k += blockDim.x){
        float v = 0.f;
        if (k < 1024)       v = Wh[(size_t)k*HID + u];
        else if (k < 1124)  v = Wx[(size_t)(k-1024)*HID + u];
        WThi[(size_t)J*KTOT + k] = (f16)v;
    }
    if (threadIdx.x == 0){
        const float* bb = (g==0)?bi_:(g==1)?bf_:(g==2)?bo_:bc_;
        biasP[J] = bb[u];
    }
}

__global__ void pack_x(const int* __restrict__ tokens, const float* __restrict__ emb,
                       f16* __restrict__ Xbuf)
{
    int bid = blockIdx.x;               // t*256 + row
    int t = bid >> 8, row = bid & 255;
    int tok = tokens[(size_t)row*STEPS + t];
    int kx = threadIdx.x;               // 0..127
    float v = (kx < EMBN) ? emb[(size_t)tok*EMBN + kx] : 0.f;
    Xbuf[(size_t)bid*XPAD + kx] = (f16)v;
}

__global__ void pack_h0(const float* __restrict__ H0, f16* __restrict__ Hb)
{
    int i = blockIdx.x*blockDim.x + threadIdx.x;
    if (i < BATCHN*HID) Hb[i] = (f16)H0[i];
}

// One k-tile's A fragments -> 4 PLAIN cached register loads (both H and X).
// Freshness: ring addressing (no address reused within a fence window) +
// agent-acquire fence (buffer_inv) every fence-interval steps — the plain-read+
// fence combination is the round-5/round-9 proven-correct protocol, amortized.
#define ISSUE(kt_, AF) do {                                                              \
    const int kb_ = w*288 + (kt_)*32;                                                    \
    if (kb_ < 1024) {                                                                    \
        const f16* hb_ = Hrd + kb_ + lhi*8;                                              \
        asm volatile("global_load_dwordx4 %0, %1, off" : "=v"(AF[0]) : "v"(hb_ + (size_t)rA[0]*HID)); \
        asm volatile("global_load_dwordx4 %0, %1, off" : "=v"(AF[1]) : "v"(hb_ + (size_t)rA[1]*HID)); \
        asm volatile("global_load_dwordx4 %0, %1, off" : "=v"(AF[2]) : "v"(hb_ + (size_t)rA[2]*HID)); \
        asm volatile("global_load_dwordx4 %0, %1, off" : "=v"(AF[3]) : "v"(hb_ + (size_t)rA[3]*HID)); \
    } else {                                                                             \
        const f16* xb_ = Xrow + (kb_ - 1024) + lhi*8;                                    \
        asm volatile("global_load_dwordx4 %0, %1, off" : "=v"(AF[0]) : "v"(xb_ + (size_t)rA[0]*XPAD)); \
        asm volatile("global_load_dwordx4 %0, %1, off" : "=v"(AF[1]) : "v"(xb_ + (size_t)rA[1]*XPAD)); \
        asm volatile("global_load_dwordx4 %0, %1, off" : "=v"(AF[2]) : "v"(xb_ + (size_t)rA[2]*XPAD)); \
        asm volatile("global_load_dwordx4 %0, %1, off" : "=v"(AF[3]) : "v"(xb_ + (size_t)rA[3]*XPAD)); \
    }                                                                                    \
} while(0)

#define WAITN(n_) do {                                                                   \
    asm volatile("s_waitcnt vmcnt(" #n_ ")" ::: "memory");                               \
    __builtin_amdgcn_sched_barrier(0);                                                   \
} while(0)

// Hi-only MFMA: 16 per k-tile.
#define MM(kt_, AF) do {                                                                 \
    _Pragma("unroll")                                                                    \
    for (int q_ = 0; q_ < 4; q_++){                                                      \
        _Pragma("unroll")                                                                \
        for (int ct_ = 0; ct_ < 4; ct_++){                                               \
            acc[q_][ct_] = __builtin_amdgcn_mfma_f32_16x16x32_f16(AF[q_], Bf[kt_][ct_], acc[q_][ct_], 0,0,0); \
        }                                                                                \
    }                                                                                    \
} while(0)

// Persistent LSTM: 256 blocks (4 bg x 64 cg) x 256 threads, 1/CU.
// Weights f16 hi-only in AGPR (144/lane). H exchange through a slot ring:
// read slot t&smask, write slot (t+1)&smask, publish sc1 (LLC authoritative),
// PLAIN cached reads (XCD-L2 broadcast among the 32+ blocks sharing a bg),
// agent-acquire fence (buffer_inv) whenever (t & fmask)==0 — one fence per
// address-reuse window. Ring mode: smask=63,fmask=63 (8 fences total).
// Fallback (small ws): smask=1,fmask=0 (= round-9 per-step-fence fingerprint).
__global__ __launch_bounds__(256, 1) void lstm_main(
    const f16* __restrict__ WThi, const f16* __restrict__ Xbuf,
    const float* __restrict__ biasP, const float* __restrict__ C0,
    f16* __restrict__ H, int smask, int fmask,
    const float* __restrict__ dw, const float* __restrict__ db,
    float* __restrict__ out, unsigned* __restrict__ flags)
{
    __shared__ f32x4 red[4*3*4*64];     // [owner][q1][ct][lane], 48KB
    __shared__ int s_bail;

    const int bid = blockIdx.x;
    const int bg = bid & 3, cg = bid >> 2;
    const int tid = threadIdx.x;
    const int w = tid >> 6, l = tid & 63, lr = l & 15, lhi = l >> 4;
    const int um = l & 3, gs = lr >> 2;
    if (tid == 0) s_bail = 0;

    // ---- persistent weights: 9 kt x 4 ct = 144 regs/lane (AGPR-resident) ----
    f16x8 Bf[9][4];
    #pragma unroll
    for (int kt = 0; kt < 9; kt++){
        int k0 = w*288 + kt*32 + lhi*8;
        #pragma unroll
        for (int ct = 0; ct < 4; ct++)
            Bf[kt][ct] = *(const f16x8*)(WThi + (size_t)(cg*64 + ct*16 + lr)*KTOT + k0);
    }
    float bs[4][4];                      // [ct][gate]
    #pragma unroll
    for (int ct = 0; ct < 4; ct++)
        #pragma unroll
        for (int g = 0; g < 4; g++)
            bs[ct][g] = biasP[cg*64 + ct*16 + g*4 + um];

    int rA[4];
    #pragma unroll
    for (int q = 0; q < 4; q++) rA[q] = bg*64 + ((w + q) & 3)*16 + lr;
    const int myrow0 = bg*64 + w*16 + lhi*4;      // kept rowtile = global rt w
    const int colW = cg*16 + gs*4 + um;           // H-store column

    float Cr[4][4];                      // [ct][r], gs-redundant
    #pragma unroll
    for (int ct = 0; ct < 4; ct++)
        #pragma unroll
        for (int r = 0; r < 4; r++)
            Cr[ct][r] = C0[(size_t)(myrow0 + r)*HID + cg*16 + ct*4 + um];

    __syncthreads();

    for (int t = 0; t < STEPS; t++){
        // ---- window fence: invalidate cached H lines before this window's
        //      plain reads (round-5/9 proven mechanism, amortized to 1/window).
        if ((t & fmask) == 0){
            __builtin_amdgcn_fence(__ATOMIC_ACQUIRE, "agent");
            __builtin_amdgcn_sched_barrier(0);
        }

        const f16* Hrd = H + (size_t)(t & smask)*HSLOT;
        f16*       Hwr = H + (size_t)((t + 1) & smask)*HSLOT;
        const f16* Xrow = Xbuf + (size_t)t*BATCHN*XPAD;

        f32x4 acc[4][4];
        #pragma unroll
        for (int q = 0; q < 4; q++)
            #pragma unroll
            for (int ct = 0; ct < 4; ct++) acc[q][ct] = (f32x4){0.f,0.f,0.f,0.f};

        // ---- 36-deep pure-register A pipeline: all 9 k-tiles in flight ----
        f16x8 A0[4], A1[4], A2[4], A3[4], A4[4], A5[4], A6[4], A7[4], A8[4];
        ISSUE(0, A0); ISSUE(1, A1); ISSUE(2, A2); ISSUE(3, A3); ISSUE(4, A4);
        ISSUE(5, A5); ISSUE(6, A6); ISSUE(7, A7); ISSUE(8, A8);

        WAITN(32); MM(0, A0);
        WAITN(28); MM(1, A1);
        WAITN(24); MM(2, A2);
        WAITN(20); MM(3, A3);
        WAITN(16); MM(4, A4);
        WAITN(12); MM(5, A5);
        WAITN(8);  MM(6, A6);
        WAITN(4);  MM(7, A7);
        WAITN(0);  MM(8, A8);

        // ---- cross-wave K reduction (kept tile q=0 <-> global rt w) ----
        #pragma unroll
        for (int q = 1; q < 4; q++){
            int o = (w + q) & 3;
            #pragma unroll
            for (int ct = 0; ct < 4; ct++)
                red[((o*3 + (q-1))*4 + ct)*64 + l] = acc[q][ct];
        }
        __syncthreads();
        #pragma unroll
        for (int q1 = 0; q1 < 3; q1++)
            #pragma unroll
            for (int ct = 0; ct < 4; ct++)
                acc[0][ct] += red[((w*3 + q1)*4 + ct)*64 + l];

        // ---- epilogue: gather gates (xor 4/8/12), update C, compute h ----
        float hall[4][4];
        #pragma unroll
        for (int ct = 0; ct < 4; ct++){
            #pragma unroll
            for (int r = 0; r < 4; r++){
                float a0 = acc[0][ct][r];
                float a1 = __shfl_xor(a0, 4, 64);
                float a2 = __shfl_xor(a0, 8, 64);
                float a3 = __shfl_xor(a0, 12, 64);
                float gi = pick4(a0,a1,a2,a3, gs    ) + bs[ct][0];
                float gf = pick4(a0,a1,a2,a3, gs ^ 1) + bs[ct][1];
                float go = pick4(a0,a1,a2,a3, gs ^ 2) + bs[ct][2];
                float gc = pick4(a0,a1,a2,a3, gs ^ 3) + bs[ct][3];
                float I = sigm(gi), F = sigm(gf), O = sigm(go), G = tanh_f(gc);
                float c = F*Cr[ct][r] + I*G;
                Cr[ct][r] = c;
                hall[ct][r] = O*tanh_f(c);
            }
        }

        // ---- H store: lane gs stores ct=gs -> each (unit,row) exactly once.
        //      sc1 write-through to LLC (authoritative for reader misses). ----
        #pragma unroll
        for (int r = 0; r < 4; r++){
            float hv = pick4(hall[0][r], hall[1][r], hall[2][r], hall[3][r], gs);
            f16 h16 = (f16)hv;
            f16* p = Hwr + (size_t)(myrow0 + r)*HID + colW;
            __hip_atomic_store(p, h16, __ATOMIC_RELAXED, __HIP_MEMORY_SCOPE_AGENT);
        }
        asm volatile("s_waitcnt vmcnt(0)" ::: "memory");
        __syncthreads();

        // ---- grid barrier: per-block flag (device scope), coalesced poll ----
        if (tid == 0)
            __hip_atomic_store(&flags[bid], (unsigned)(t+1), __ATOMIC_RELAXED, __HIP_MEMORY_SCOPE_AGENT);
        if (w == 0){
            unsigned tgt = (unsigned)(t+1), guard = 0;
            for (;;){
                unsigned f0 = __hip_atomic_load(&flags[l      ], __ATOMIC_RELAXED, __HIP_MEMORY_SCOPE_AGENT);
                unsigned f1 = __hip_atomic_load(&flags[l +  64], __ATOMIC_RELAXED, __HIP_MEMORY_SCOPE_AGENT);
                unsigned f2 = __hip_atomic_load(&flags[l + 128], __ATOMIC_RELAXED, __HIP_MEMORY_SCOPE_AGENT);
                unsigned f3 = __hip_atomic_load(&flags[l + 192], __ATOMIC_RELAXED, __HIP_MEMORY_SCOPE_AGENT);
                bool ok = (f0 >= tgt) && (f1 >= tgt) && (f2 >= tgt) && (f3 >= tgt);
                if (__all(ok)) break;
                if (++guard > 2000000u){ s_bail = 1; break; }
                __builtin_amdgcn_s_sleep(1);
            }
        }
        __syncthreads();
        if (s_bail) break;
    }

    // ---- final dense: H(511) lives in slot (STEPS & smask) == 0 for both
    //      smask=63 and smask=1. sc1 reads (LLC authoritative). ----
    if (cg == 0){
        const f16* Hf = H;                       // slot 0
        int r = tid >> 2, j = (tid >> 1) & 1, half = tid & 1;
        int row = bg*64 + r;
        const f16* hrow = Hf + (size_t)row*HID + half*512;
        float s = 0.f;
        for (int v = 0; v < 64; v++){
            f16x8 h8;
            asm volatile("global_load_dwordx4 %0, %1, off sc1" : "=v"(h8) : "v"(hrow + v*8));
            asm volatile("s_waitcnt vmcnt(0)" ::: "memory");
            #pragma unroll
            for (int e = 0; e < 8; e++)
                s += (float)h8[e] * dw[(size_t)(half*512 + v*8 + e)*2 + j];
        }
        s += __shfl_xor(s, 1, 64);
        if (half == 0) out[(size_t)row*2 + j] = s + db[j];
    }
}

extern "C" void kernel_launch(void* const* d_in, const int* in_sizes, int n_in,
                              void* d_out, int out_size, void* d_ws, size_t ws_size,
                              hipStream_t stream)
{
    const int*   tokens = (const int*)d_in[0];
    const float* H0  = (const float*)d_in[1];
    const float* C0  = (const float*)d_in[2];
    const float* Wxi = (const float*)d_in[3];
    const float* Whi = (const float*)d_in[4];
    const float* bi  = (const float*)d_in[5];
    const float* Wxf = (const float*)d_in[6];
    const float* Whf = (const float*)d_in[7];
    const float* bf  = (const float*)d_in[8];
    const float* Wxo = (const float*)d_in[9];
    const float* Who = (const float*)d_in[10];
    const float* bo  = (const float*)d_in[11];
    const float* Wxc = (const float*)d_in[12];
    const float* Whc = (const float*)d_in[13];
    const float* bc  = (const float*)d_in[14];
    const float* emb = (const float*)d_in[15];
    const float* dw  = (const float*)d_in[16];
    const float* db  = (const float*)d_in[17];
    float* out = (float*)d_out;

    char* ws = (char*)d_ws;
    size_t off = 0;
    auto alloc = [&](size_t bytes){ void* p = ws + off; off += (bytes + 255) & ~(size_t)255; return p; };
    f16* WThi = (f16*)alloc((size_t)4096*KTOT*2);
    f16* Xbuf = (f16*)alloc((size_t)STEPS*BATCHN*XPAD*2);
    float* biasP = (float*)alloc(4096*sizeof(float));
    unsigned* flags = (unsigned*)alloc(NBLK*sizeof(unsigned));

    // Ring mode: 64 H slots (33.5MB), fence every 64 steps (8 total).
    // Fallback (small ws): 2-slot ping-pong + fence EVERY step = round-9
    // behavior (~10.5ms fingerprint, proven correct) so the outcome is
    // unambiguous either way.
    size_t ringBytes = (size_t)64*HSLOT*2;
    int smask, fmask;
    f16* H;
    if (off + ringBytes <= ws_size){
        H = (f16*)alloc(ringBytes);
        smask = 63; fmask = 63;
    } else {
        H = (f16*)alloc((size_t)2*HSLOT*2);
        smask = 1; fmask = 0;
    }
    if (off > ws_size) return;   // workspace too small: fail loud

    hipMemsetAsync(flags, 0, NBLK*sizeof(unsigned), stream);
    pack_w<<<4096, 256, 0, stream>>>(Whi,Whf,Who,Whc, Wxi,Wxf,Wxo,Wxc, bi,bf,bo,bc,
                                     WThi, biasP);
    pack_x<<<STEPS*BATCHN, 128, 0, stream>>>(tokens, emb, Xbuf);
    pack_h0<<<(BATCHN*HID + 255)/256, 256, 0, stream>>>(H0, H);   // slot 0
    lstm_main<<<NBLK, 256, 0, stream>>>(WThi, Xbuf, biasP, C0, H, smask, fmask,
                                        dw, db, out, flags);
}

// Round 14
// 5732.935 us; speedup vs baseline: 1.8513x; 1.1877x over previous
//
#include <hip/hip_runtime.h>

typedef _Float16 f16;
typedef _Float16 f16x8 __attribute__((ext_vector_type(8)));
typedef float f32x4 __attribute__((ext_vector_type(4)));

#define STEPS 512
#define BATCHN 256
#define HID 1024
#define EMBN 100
#define KTOT 1152
#define XPAD 128
#define NBLK 256
#define HSLOT ((size_t)BATCHN*HID)     // f16 elems per H snapshot (512KB)

__device__ __forceinline__ float sigm(float x){ return 1.f/(1.f+__expf(-x)); }
__device__ __forceinline__ float tanh_f(float x){
    float e = __expf(2.f*fabsf(x));
    float r = 1.f - 2.f/(e+1.f);
    return x >= 0.f ? r : -r;
}
// select {a0,a1,a2,a3}[idx] without runtime-indexed array (rule #20)
__device__ __forceinline__ float pick4(float a0, float a1, float a2, float a3, int idx){
    float t0 = (idx & 1) ? a1 : a0;
    float t1 = (idx & 1) ? a3 : a2;
    return (idx & 2) ? t1 : t0;
}

// Pack W_h(1024 rows)+W_x(100)+pad -> WT[4096][1152] f16 (hi only; validated
// round 11: absmax 1.22e-4). Col J = cg*64+ct*16+g*4+um -> unit u. Also bias[J].
__global__ void pack_w(const float* __restrict__ Whi_, const float* __restrict__ Whf_,
                       const float* __restrict__ Who_, const float* __restrict__ Whc_,
                       const float* __restrict__ Wxi_, const float* __restrict__ Wxf_,
                       const float* __restrict__ Wxo_, const float* __restrict__ Wxc_,
                       const float* __restrict__ bi_, const float* __restrict__ bf_,
                       const float* __restrict__ bo_, const float* __restrict__ bc_,
                       f16* __restrict__ WThi, float* __restrict__ biasP)
{
    int J = blockIdx.x;                 // 0..4095
    int cg = J >> 6, ct = (J >> 4) & 3, g = (J >> 2) & 3, um = J & 3;
    int u = cg*16 + ct*4 + um;
    const float* Wh = (g==0)?Whi_:(g==1)?Whf_:(g==2)?Who_:Whc_;
    const float* Wx = (g==0)?Wxi_:(g==1)?Wxf_:(g==2)?Wxo_:Wxc_;
    for (int k = threadIdx.x; k < KTOT; k += blockDim.x){
        float v = 0.f;
        if (k < 1024)       v = Wh[(size_t)k*HID + u];
        else if (k < 1124)  v = Wx[(size_t)(k-1024)*HID + u];
        WThi[(size_t)J*KTOT + k] = (f16)v;
    }
    if (threadIdx.x == 0){
        const float* bb = (g==0)?bi_:(g==1)?bf_:(g==2)?bo_:bc_;
        biasP[J] = bb[u];
    }
}

__global__ void pack_x(const int* __restrict__ tokens, const float* __restrict__ emb,
                       f16* __restrict__ Xbuf)
{
    int bid = blockIdx.x;               // t*256 + row
    int t = bid >> 8, row = bid & 255;
    int tok = tokens[(size_t)row*STEPS + t];
    int kx = threadIdx.x;               // 0..127
    float v = (kx < EMBN) ? emb[(size_t)tok*EMBN + kx] : 0.f;
    Xbuf[(size_t)bid*XPAD + kx] = (f16)v;
}

// H0 -> blocked slot-0 layout: elem(bg,rloc,col) =
//   bg*65536 + (col>>4)*1024 + rloc*16 + (col&15)
__global__ void pack_h0(const float* __restrict__ H0, f16* __restrict__ Hb)
{
    int i = blockIdx.x*blockDim.x + threadIdx.x;
    if (i < BATCHN*HID){
        int row = i >> 10, col = i & 1023;
        size_t d = (size_t)(row >> 6)*65536 + (size_t)(col >> 4)*1024
                 + (size_t)(row & 63)*16 + (col & 15);
        Hb[d] = (f16)H0[i];
    }
}

// One k-tile's A fragments -> 4 PLAIN cached register loads (both H and X).
// H uses the blocked layout: chunk=(k>>4), within-chunk = rloc*16 + (k&15).
// Freshness: ring addressing + agent-acquire fence every 64 steps (round-13
// proven protocol, unchanged).
#define ISSUE(kt_, AF) do {                                                              \
    const int kb_ = w*288 + (kt_)*32;                                                    \
    if (kb_ < 1024) {                                                                    \
        const f16* hb_ = Hrd + ((kb_ >> 4) + (lhi >> 1))*1024 + (lhi & 1)*8;             \
        asm volatile("global_load_dwordx4 %0, %1, off" : "=v"(AF[0]) : "v"(hb_ + rS[0])); \
        asm volatile("global_load_dwordx4 %0, %1, off" : "=v"(AF[1]) : "v"(hb_ + rS[1])); \
        asm volatile("global_load_dwordx4 %0, %1, off" : "=v"(AF[2]) : "v"(hb_ + rS[2])); \
        asm volatile("global_load_dwordx4 %0, %1, off" : "=v"(AF[3]) : "v"(hb_ + rS[3])); \
    } else {                                                                             \
        const f16* xb_ = Xrow + (kb_ - 1024) + lhi*8;                                    \
        asm volatile("global_load_dwordx4 %0, %1, off" : "=v"(AF[0]) : "v"(xb_ + (size_t)rA[0]*XPAD)); \
        asm volatile("global_load_dwordx4 %0, %1, off" : "=v"(AF[1]) : "v"(xb_ + (size_t)rA[1]*XPAD)); \
        asm volatile("global_load_dwordx4 %0, %1, off" : "=v"(AF[2]) : "v"(xb_ + (size_t)rA[2]*XPAD)); \
        asm volatile("global_load_dwordx4 %0, %1, off" : "=v"(AF[3]) : "v"(xb_ + (size_t)rA[3]*XPAD)); \
    }                                                                                    \
} while(0)

#define WAITN(n_) do {                                                                   \
    asm volatile("s_waitcnt vmcnt(" #n_ ")" ::: "memory");                               \
    __builtin_amdgcn_sched_barrier(0);                                                   \
} while(0)

// Hi-only MFMA: 16 per k-tile.
#define MM(kt_, AF) do {                                                                 \
    _Pragma("unroll")                                                                    \
    for (int q_ = 0; q_ < 4; q_++){                                                      \
        _Pragma("unroll")                                                                \
        for (int ct_ = 0; ct_ < 4; ct_++){                                               \
            acc[q_][ct_] = __builtin_amdgcn_mfma_f32_16x16x32_f16(AF[q_], Bf[kt_][ct_], acc[q_][ct_], 0,0,0); \
        }                                                                                \
    }                                                                                    \
} while(0)

// Persistent LSTM: 256 blocks (4 bg x 64 cg) x 256 threads, 1/CU.
// Weights f16 hi-only in AGPR (144/lane). H in BLOCKED layout: each block's
// 64rows x 16cols = one contiguous 2KB chunk -> publish is 256 coalesced 8B
// sc1 stores (full 128B lines; no partial-line write-through RMW). Reads
// plain-cached through the 64-slot ring + fence-every-64 (round-13 protocol).
// Barrier per-bg (bg groups share nothing): 64 flags, 1 poll load/lane.
__global__ __launch_bounds__(256, 1) void lstm_main(
    const f16* __restrict__ WThi, const f16* __restrict__ Xbuf,
    const float* __restrict__ biasP, const float* __restrict__ C0,
    f16* __restrict__ H, int smask, int fmask,
    const float* __restrict__ dw, const float* __restrict__ db,
    float* __restrict__ out, unsigned* __restrict__ flags)
{
    __shared__ f32x4 red[4*3*4*64];     // [owner][q1][ct][lane], 48KB
    __shared__ f16 hstage[64*16];       // block's H tile, row-major [64][16], 2KB
    __shared__ int s_bail;

    const int bid = blockIdx.x;
    const int bg = bid & 3, cg = bid >> 2;
    const int tid = threadIdx.x;
    const int w = tid >> 6, l = tid & 63, lr = l & 15, lhi = l >> 4;
    const int um = l & 3, gs = lr >> 2;
    if (tid == 0) s_bail = 0;

    // ---- persistent weights: 9 kt x 4 ct = 144 regs/lane (AGPR-resident) ----
    f16x8 Bf[9][4];
    #pragma unroll
    for (int kt = 0; kt < 9; kt++){
        int k0 = w*288 + kt*32 + lhi*8;
        #pragma unroll
        for (int ct = 0; ct < 4; ct++)
            Bf[kt][ct] = *(const f16x8*)(WThi + (size_t)(cg*64 + ct*16 + lr)*KTOT + k0);
    }
    float bs[4][4];                      // [ct][gate]
    #pragma unroll
    for (int ct = 0; ct < 4; ct++)
        #pragma unroll
        for (int g = 0; g < 4; g++)
            bs[ct][g] = biasP[cg*64 + ct*16 + g*4 + um];

    int rA[4], rS[4];
    #pragma unroll
    for (int q = 0; q < 4; q++){
        int rloc = ((w + q) & 3)*16 + lr;
        rA[q] = bg*64 + rloc;            // X row (row-major Xbuf)
        rS[q] = rloc*16;                 // H blocked within-chunk offset
    }
    const int myrow0 = bg*64 + w*16 + lhi*4;      // kept rowtile = global rt w

    float Cr[4][4];                      // [ct][r], gs-redundant
    #pragma unroll
    for (int ct = 0; ct < 4; ct++)
        #pragma unroll
        for (int r = 0; r < 4; r++)
            Cr[ct][r] = C0[(size_t)(myrow0 + r)*HID + cg*16 + ct*4 + um];

    __syncthreads();

    for (int t = 0; t < STEPS; t++){
        // ---- window fence (ring reuse): round-13 proven, 8 total ----
        if ((t & fmask) == 0){
            __builtin_amdgcn_fence(__ATOMIC_ACQUIRE, "agent");
            __builtin_amdgcn_sched_barrier(0);
        }

        const f16* Hrd = H + (size_t)(t & smask)*HSLOT + (bg << 16);
        f16*       Hwr = H + (size_t)((t + 1) & smask)*HSLOT + (bg << 16) + (cg << 10);
        const f16* Xrow = Xbuf + (size_t)t*BATCHN*XPAD;

        f32x4 acc[4][4];
        #pragma unroll
        for (int q = 0; q < 4; q++)
            #pragma unroll
            for (int ct = 0; ct < 4; ct++) acc[q][ct] = (f32x4){0.f,0.f,0.f,0.f};

        // ---- 36-deep pure-register A pipeline: all 9 k-tiles in flight ----
        f16x8 A0[4], A1[4], A2[4], A3[4], A4[4], A5[4], A6[4], A7[4], A8[4];
        ISSUE(0, A0); ISSUE(1, A1); ISSUE(2, A2); ISSUE(3, A3); ISSUE(4, A4);
        ISSUE(5, A5); ISSUE(6, A6); ISSUE(7, A7); ISSUE(8, A8);

        WAITN(32); MM(0, A0);
        WAITN(28); MM(1, A1);
        WAITN(24); MM(2, A2);
        WAITN(20); MM(3, A3);
        WAITN(16); MM(4, A4);
        WAITN(12); MM(5, A5);
        WAITN(8);  MM(6, A6);
        WAITN(4);  MM(7, A7);
        WAITN(0);  MM(8, A8);

        // ---- cross-wave K reduction (kept tile q=0 <-> global rt w) ----
        #pragma unroll
        for (int q = 1; q < 4; q++){
            int o = (w + q) & 3;
            #pragma unroll
            for (int ct = 0; ct < 4; ct++)
                red[((o*3 + (q-1))*4 + ct)*64 + l] = acc[q][ct];
        }
        __syncthreads();
        #pragma unroll
        for (int q1 = 0; q1 < 3; q1++)
            #pragma unroll
            for (int ct = 0; ct < 4; ct++)
                acc[0][ct] += red[((w*3 + q1)*4 + ct)*64 + l];

        // ---- epilogue: gather gates (xor 4/8/12), update C, h -> LDS tile ----
        #pragma unroll
        for (int ct = 0; ct < 4; ct++){
            #pragma unroll
            for (int r = 0; r < 4; r++){
                float a0 = acc[0][ct][r];
                float a1 = __shfl_xor(a0, 4, 64);
                float a2 = __shfl_xor(a0, 8, 64);
                float a3 = __shfl_xor(a0, 12, 64);
                float gi = pick4(a0,a1,a2,a3, gs    ) + bs[ct][0];
                float gf = pick4(a0,a1,a2,a3, gs ^ 1) + bs[ct][1];
                float go = pick4(a0,a1,a2,a3, gs ^ 2) + bs[ct][2];
                float gc = pick4(a0,a1,a2,a3, gs ^ 3) + bs[ct][3];
                float I = sigm(gi), F = sigm(gf), O = sigm(go), G = tanh_f(gc);
                float c = F*Cr[ct][r] + I*G;
                Cr[ct][r] = c;
                float h = O*tanh_f(c);
                // lane gs owns ct == gs -> (row w*16+lhi*4+r, col lr) exactly once
                if (ct == gs)
                    hstage[(w*16 + lhi*4 + r)*16 + lr] = (f16)h;
            }
        }
        __syncthreads();

        // ---- publish: 256 x 8B coalesced sc1 stores = 16 full 128B lines ----
        {
            uint2 hv2 = *(const uint2*)(hstage + tid*4);
            const f16* dst = Hwr + tid*4;
            asm volatile("global_store_dwordx2 %0, %1, off sc1" :: "v"(dst), "v"(hv2) : "memory");
        }
        asm volatile("s_waitcnt vmcnt(0)" ::: "memory");
        __syncthreads();

        // ---- per-bg barrier: 64 flags, 1 poll load per lane ----
        if (tid == 0)
            __hip_atomic_store(&flags[bg*64 + cg], (unsigned)(t+1), __ATOMIC_RELAXED, __HIP_MEMORY_SCOPE_AGENT);
        if (w == 0){
            unsigned tgt = (unsigned)(t+1), guard = 0;
            for (;;){
                unsigned f0 = __hip_atomic_load(&flags[bg*64 + l], __ATOMIC_RELAXED, __HIP_MEMORY_SCOPE_AGENT);
                if (__all(f0 >= tgt)) break;
                if (++guard > 2000000u){ s_bail = 1; break; }
                __builtin_amdgcn_s_sleep(1);
            }
        }
        __syncthreads();
        if (s_bail) break;
    }

    // ---- final dense: H(511) in slot (STEPS & smask)==0, blocked layout ----
    if (cg == 0){
        const f16* Hf = H + (bg << 16);          // slot 0, this bg's region
        int r = tid >> 2, j = (tid >> 1) & 1, half = tid & 1;
        int row = bg*64 + r;
        float s = 0.f;
        for (int v = 0; v < 64; v++){
            int chunk = half*32 + (v >> 1), koff = (v & 1)*8;
            const f16* hp = Hf + chunk*1024 + r*16 + koff;
            f16x8 h8;
            asm volatile("global_load_dwordx4 %0, %1, off sc1" : "=v"(h8) : "v"(hp));
            asm volatile("s_waitcnt vmcnt(0)" ::: "memory");
            #pragma unroll
            for (int e = 0; e < 8; e++)
                s += (float)h8[e] * dw[(size_t)(half*512 + v*8 + e)*2 + j];
        }
        s += __shfl_xor(s, 1, 64);
        if (half == 0) out[(size_t)row*2 + j] = s + db[j];
    }
}

extern "C" void kernel_launch(void* const* d_in, const int* in_sizes, int n_in,
                              void* d_out, int out_size, void* d_ws, size_t ws_size,
                              hipStream_t stream)
{
    const int*   tokens = (const int*)d_in[0];
    const float* H0  = (const float*)d_in[1];
    const float* C0  = (const float*)d_in[2];
    const float* Wxi = (const float*)d_in[3];
    const float* Whi = (const float*)d_in[4];
    const float* bi  = (const float*)d_in[5];
    const float* Wxf = (const float*)d_in[6];
    const float* Whf = (const float*)d_in[7];
    const float* bf  = (const float*)d_in[8];
    const float* Wxo = (const float*)d_in[9];
    const float* Who = (const float*)d_in[10];
    const float* bo  = (const float*)d_in[11];
    const float* Wxc = (const float*)d_in[12];
    const float* Whc = (const float*)d_in[13];
    const float* bc  = (const float*)d_in[14];
    const float* emb = (const float*)d_in[15];
    const float* dw  = (const float*)d_in[16];
    const float* db  = (const float*)d_in[17];
    float* out = (float*)d_out;

    char* ws = (char*)d_ws;
    size_t off = 0;
    auto alloc = [&](size_t bytes){ void* p = ws + off; off += (bytes + 255) & ~(size_t)255; return p; };
    f16* WThi = (f16*)alloc((size_t)4096*KTOT*2);
    f16* Xbuf = (f16*)alloc((size_t)STEPS*BATCHN*XPAD*2);
    float* biasP = (float*)alloc(4096*sizeof(float));
    unsigned* flags = (unsigned*)alloc(NBLK*sizeof(unsigned));

    // Ring mode: 64 H slots (33.5MB), fence every 64 steps. Fallback (small
    // ws): 2-slot ping-pong + fence every step (round-9 ~10.5ms fingerprint).
    size_t ringBytes = (size_t)64*HSLOT*2;
    int smask, fmask;
    f16* H;
    if (off + ringBytes <= ws_size){
        H = (f16*)alloc(ringBytes);
        smask = 63; fmask = 63;
    } else {
        H = (f16*)alloc((size_t)2*HSLOT*2);
        smask = 1; fmask = 0;
    }
    if (off > ws_size) return;   // workspace too small: fail loud

    hipMemsetAsync(flags, 0, NBLK*sizeof(unsigned), stream);
    pack_w<<<4096, 256, 0, stream>>>(Whi,Whf,Who,Whc, Wxi,Wxf,Wxo,Wxc, bi,bf,bo,bc,
                                     WThi, biasP);
    pack_x<<<STEPS*BATCHN, 128, 0, stream>>>(tokens, emb, Xbuf);
    pack_h0<<<(BATCHN*HID + 255)/256, 256, 0, stream>>>(H0, H);   // slot 0
    lstm_main<<<NBLK, 256, 0, stream>>>(WThi, Xbuf, biasP, C0, H, smask, fmask,
                                        dw, db, out, flags);
}

// Round 15
// 5207.610 us; speedup vs baseline: 2.0381x; 1.1009x over previous
//
#include <hip/hip_runtime.h>

typedef _Float16 f16;
typedef _Float16 f16x8 __attribute__((ext_vector_type(8)));
typedef float f32x4 __attribute__((ext_vector_type(4)));

#define STEPS 512
#define BATCHN 256
#define HID 1024
#define EMBN 100
#define KTOT 1152
#define XPAD 128
#define NBLK 512
#define HSLOT ((size_t)BATCHN*HID)     // f16 elems per H snapshot (512KB)

__device__ __forceinline__ float sigm(float x){ return 1.f/(1.f+__expf(-x)); }
__device__ __forceinline__ float tanh_f(float x){
    float e = __expf(2.f*fabsf(x));
    float r = 1.f - 2.f/(e+1.f);
    return x >= 0.f ? r : -r;
}
// select {a0,a1,a2,a3}[idx] without runtime-indexed array (rule #20)
__device__ __forceinline__ float pick4(float a0, float a1, float a2, float a3, int idx){
    float t0 = (idx & 1) ? a1 : a0;
    float t1 = (idx & 1) ? a3 : a2;
    return (idx & 2) ? t1 : t0;
}

// Pack W_h(1024)+W_x(100)+pad -> WT[4096][1152] f16 hi-only (validated r11).
// Col J = cg*32 + ct*16 + g*4 + um (cg 0..127, ct 0..1) -> unit u = cg*8+ct*4+um.
__global__ void pack_w(const float* __restrict__ Whi_, const float* __restrict__ Whf_,
                       const float* __restrict__ Who_, const float* __restrict__ Whc_,
                       const float* __restrict__ Wxi_, const float* __restrict__ Wxf_,
                       const float* __restrict__ Wxo_, const float* __restrict__ Wxc_,
                       const float* __restrict__ bi_, const float* __restrict__ bf_,
                       const float* __restrict__ bo_, const float* __restrict__ bc_,
                       f16* __restrict__ WThi, float* __restrict__ biasP)
{
    int J = blockIdx.x;                 // 0..4095
    int cg = J >> 5, ct = (J >> 4) & 1, g = (J >> 2) & 3, um = J & 3;
    int u = cg*8 + ct*4 + um;
    const float* Wh = (g==0)?Whi_:(g==1)?Whf_:(g==2)?Who_:Whc_;
    const float* Wx = (g==0)?Wxi_:(g==1)?Wxf_:(g==2)?Wxo_:Wxc_;
    for (int k = threadIdx.x; k < KTOT; k += blockDim.x){
        float v = 0.f;
        if (k < 1024)       v = Wh[(size_t)k*HID + u];
        else if (k < 1124)  v = Wx[(size_t)(k-1024)*HID + u];
        WThi[(size_t)J*KTOT + k] = (f16)v;
    }
    if (threadIdx.x == 0){
        const float* bb = (g==0)?bi_:(g==1)?bf_:(g==2)?bo_:bc_;
        biasP[J] = bb[u];
    }
}

__global__ void pack_x(const int* __restrict__ tokens, const float* __restrict__ emb,
                       f16* __restrict__ Xbuf)
{
    int bid = blockIdx.x;               // t*256 + row
    int t = bid >> 8, row = bid & 255;
    int tok = tokens[(size_t)row*STEPS + t];
    int kx = threadIdx.x;               // 0..127
    float v = (kx < EMBN) ? emb[(size_t)tok*EMBN + kx] : 0.f;
    Xbuf[(size_t)bid*XPAD + kx] = (f16)v;
}

// H0 -> blocked-8 slot-0 layout:
//   elem(row,col) = (row>>6)*65536 + (col>>3)*512 + (row&63)*8 + (col&7)
__global__ void pack_h0(const float* __restrict__ H0, f16* __restrict__ Hb)
{
    int i = blockIdx.x*blockDim.x + threadIdx.x;
    if (i < BATCHN*HID){
        int row = i >> 10, col = i & 1023;
        size_t d = (size_t)(row >> 6)*65536 + (size_t)(col >> 3)*512
                 + (size_t)(row & 63)*8 + (col & 7);
        Hb[d] = (f16)H0[i];
    }
}

// One k-tile's A fragments -> 4 PLAIN cached loads. H in blocked-8 layout:
// chunk = (k>>3)+lhi (8 cols/chunk), within-chunk row offset rloc*8 (16B/row).
// Freshness: ring + fence-every-64 (round-13/14 proven protocol).
#define ISSUE(kt_, AF) do {                                                              \
    const int kb_ = w*288 + (kt_)*32;                                                    \
    if (kb_ < 1024) {                                                                    \
        const f16* hb_ = Hrd + ((kb_ >> 3) + lhi)*512;                                   \
        asm volatile("global_load_dwordx4 %0, %1, off" : "=v"(AF[0]) : "v"(hb_ + rS[0])); \
        asm volatile("global_load_dwordx4 %0, %1, off" : "=v"(AF[1]) : "v"(hb_ + rS[1])); \
        asm volatile("global_load_dwordx4 %0, %1, off" : "=v"(AF[2]) : "v"(hb_ + rS[2])); \
        asm volatile("global_load_dwordx4 %0, %1, off" : "=v"(AF[3]) : "v"(hb_ + rS[3])); \
    } else {                                                                             \
        const f16* xb_ = Xrow + (kb_ - 1024) + lhi*8;                                    \
        asm volatile("global_load_dwordx4 %0, %1, off" : "=v"(AF[0]) : "v"(xb_ + rX[0])); \
        asm volatile("global_load_dwordx4 %0, %1, off" : "=v"(AF[1]) : "v"(xb_ + rX[1])); \
        asm volatile("global_load_dwordx4 %0, %1, off" : "=v"(AF[2]) : "v"(xb_ + rX[2])); \
        asm volatile("global_load_dwordx4 %0, %1, off" : "=v"(AF[3]) : "v"(xb_ + rX[3])); \
    }                                                                                    \
} while(0)

#define WAITK(kt_) do {                                                                  \
    if ((kt_) < 7)       asm volatile("s_waitcnt vmcnt(8)" ::: "memory");                \
    else if ((kt_) == 7) asm volatile("s_waitcnt vmcnt(4)" ::: "memory");                \
    else                 asm volatile("s_waitcnt vmcnt(0)" ::: "memory");                \
    __builtin_amdgcn_sched_barrier(0);                                                   \
} while(0)

// Hi-only MFMA: 4 q-tiles x 2 ct = 8 per k-tile.
#define MM(kt_, AF) do {                                                                 \
    _Pragma("unroll")                                                                    \
    for (int q_ = 0; q_ < 4; q_++){                                                      \
        _Pragma("unroll")                                                                \
        for (int ct_ = 0; ct_ < 2; ct_++){                                               \
            acc[q_][ct_] = __builtin_amdgcn_mfma_f32_16x16x32_f16(AF[q_], Bf[kt_][ct_], acc[q_][ct_], 0,0,0); \
        }                                                                                \
    }                                                                                    \
} while(0)

// Persistent LSTM: 512 blocks (4 bg x 128 cg) x 256 threads, 2 blocks/CU.
// bg = (bid>>7)&3 -> co-resident pair (b, b+256) lands on DIFFERENT bgs:
// while one recurrence waits at its barrier, the other computes (latency
// hiding via block-level SMT). Weights f16 hi-only (72 regs/lane) + acc in
// AGPR; round-4 3-buffer/12-deep A pipeline. H in blocked-8 layout, 64-slot
// ring, plain reads + fence-every-64, coalesced 1KB sc1 publish, per-bg flags.
__global__ __launch_bounds__(256, 2) void lstm_main(
    const f16* __restrict__ WThi, const f16* __restrict__ Xbuf,
    const float* __restrict__ biasP, const float* __restrict__ C0,
    f16* __restrict__ H, int smask, int fmask,
    const float* __restrict__ dw, const float* __restrict__ db,
    float* __restrict__ out, unsigned* __restrict__ flags)
{
    __shared__ f32x4 red[4*3*2*64];     // [owner4][q1=3][ct2][lane64], 24KB
    __shared__ f16 hstage[64*8];        // block's H tile [64 rows][8 cols], 1KB
    __shared__ int s_bail;

    const int bid = blockIdx.x;
    const int bg = (bid >> 7) & 3, cg = bid & 127;
    const int tid = threadIdx.x;
    const int w = tid >> 6, l = tid & 63, lr = l & 15, lhi = l >> 4;
    const int um = l & 3, gs = lr >> 2;
    if (tid == 0) s_bail = 0;

    // ---- persistent weights: 9 kt x 2 ct = 72 regs/lane (AGPR-resident) ----
    f16x8 Bf[9][2];
    #pragma unroll
    for (int kt = 0; kt < 9; kt++){
        int k0 = w*288 + kt*32 + lhi*8;
        #pragma unroll
        for (int ct = 0; ct < 2; ct++)
            Bf[kt][ct] = *(const f16x8*)(WThi + (size_t)(cg*32 + ct*16 + lr)*KTOT + k0);
    }
    float bs[2][4];                      // [ct][gate]
    #pragma unroll
    for (int ct = 0; ct < 2; ct++)
        #pragma unroll
        for (int g = 0; g < 4; g++)
            bs[ct][g] = biasP[cg*32 + ct*16 + g*4 + um];

    int rS[4], rX[4];
    #pragma unroll
    for (int q = 0; q < 4; q++){
        int rloc = ((w + q) & 3)*16 + lr;
        rS[q] = rloc*8;                  // blocked-8 within-chunk offset
        rX[q] = (bg*64 + rloc)*XPAD;     // row-major Xbuf
    }
    const int myrow0 = bg*64 + w*16 + lhi*4;      // kept rowtile = global rt w

    float Cr[2][4];                      // [ct][r], gs-redundant
    #pragma unroll
    for (int ct = 0; ct < 2; ct++)
        #pragma unroll
        for (int r = 0; r < 4; r++)
            Cr[ct][r] = C0[(size_t)(myrow0 + r)*HID + cg*8 + ct*4 + um];

    __syncthreads();

    for (int t = 0; t < STEPS; t++){
        // ---- window fence (ring reuse): 8 total, proven r13/14 ----
        if ((t & fmask) == 0){
            __builtin_amdgcn_fence(__ATOMIC_ACQUIRE, "agent");
            __builtin_amdgcn_sched_barrier(0);
        }

        const f16* Hrd = H + (size_t)(t & smask)*HSLOT + bg*65536;
        f16*       Hwr = H + (size_t)((t + 1) & smask)*HSLOT + bg*65536 + cg*512;
        const f16* Xrow = Xbuf + (size_t)t*BATCHN*XPAD;

        f32x4 acc[4][2];
        #pragma unroll
        for (int q = 0; q < 4; q++)
            #pragma unroll
            for (int ct = 0; ct < 2; ct++) acc[q][ct] = (f32x4){0.f,0.f,0.f,0.f};

        // ---- 12-deep 3-buffer A pipeline (round-4 proven structure) ----
        f16x8 Aa[4], Ab[4], Ac[4];
        ISSUE(0, Aa);
        ISSUE(1, Ab);
        #pragma unroll
        for (int kt = 0; kt < 9; kt++){
            if ((kt % 3) == 0){
                if (kt < 7) ISSUE(kt+2, Ac);
                WAITK(kt); MM(kt, Aa);
            } else if ((kt % 3) == 1){
                if (kt < 7) ISSUE(kt+2, Aa);
                WAITK(kt); MM(kt, Ab);
            } else {
                if (kt < 7) ISSUE(kt+2, Ab);
                WAITK(kt); MM(kt, Ac);
            }
        }

        // ---- cross-wave K reduction (kept tile q=0 <-> global rt w) ----
        #pragma unroll
        for (int q = 1; q < 4; q++){
            int o = (w + q) & 3;
            #pragma unroll
            for (int ct = 0; ct < 2; ct++)
                red[((o*3 + (q-1))*2 + ct)*64 + l] = acc[q][ct];
        }
        __syncthreads();
        #pragma unroll
        for (int q1 = 0; q1 < 3; q1++)
            #pragma unroll
            for (int ct = 0; ct < 2; ct++)
                acc[0][ct] += red[((w*3 + q1)*2 + ct)*64 + l];

        // ---- epilogue: gather gates (xor 4/8/12), update C, h -> LDS tile ----
        #pragma unroll
        for (int ct = 0; ct < 2; ct++){
            #pragma unroll
            for (int r = 0; r < 4; r++){
                float a0 = acc[0][ct][r];
                float a1 = __shfl_xor(a0, 4, 64);
                float a2 = __shfl_xor(a0, 8, 64);
                float a3 = __shfl_xor(a0, 12, 64);
                float gi = pick4(a0,a1,a2,a3, gs    ) + bs[ct][0];
                float gf = pick4(a0,a1,a2,a3, gs ^ 1) + bs[ct][1];
                float go = pick4(a0,a1,a2,a3, gs ^ 2) + bs[ct][2];
                float gc = pick4(a0,a1,a2,a3, gs ^ 3) + bs[ct][3];
                float I = sigm(gi), F = sigm(gf), O = sigm(go), G = tanh_f(gc);
                float c = F*Cr[ct][r] + I*G;
                Cr[ct][r] = c;
                float h = O*tanh_f(c);
                // lane gs owns ct == gs -> (row, col gs*4+um) exactly once
                if (ct == gs)
                    hstage[(w*16 + lhi*4 + r)*8 + gs*4 + um] = (f16)h;
            }
        }
        __syncthreads();

        // ---- publish: 256 x 4B coalesced sc1 stores = 8 full 128B lines ----
        {
            unsigned hv = *(const unsigned*)(hstage + tid*2);
            const f16* dst = Hwr + tid*2;
            asm volatile("global_store_dword %0, %1, off sc1" :: "v"(dst), "v"(hv) : "memory");
        }
        asm volatile("s_waitcnt vmcnt(0)" ::: "memory");
        __syncthreads();

        // ---- per-bg barrier: 128 flags, 2 poll loads per lane ----
        if (tid == 0)
            __hip_atomic_store(&flags[bg*128 + cg], (unsigned)(t+1), __ATOMIC_RELAXED, __HIP_MEMORY_SCOPE_AGENT);
        if (w == 0){
            unsigned tgt = (unsigned)(t+1), guard = 0;
            for (;;){
                unsigned f0 = __hip_atomic_load(&flags[bg*128 + l     ], __ATOMIC_RELAXED, __HIP_MEMORY_SCOPE_AGENT);
                unsigned f1 = __hip_atomic_load(&flags[bg*128 + l + 64], __ATOMIC_RELAXED, __HIP_MEMORY_SCOPE_AGENT);
                if (__all((f0 >= tgt) && (f1 >= tgt))) break;
                if (++guard > 2000000u){ s_bail = 1; break; }
                __builtin_amdgcn_s_sleep(1);
            }
        }
        __syncthreads();
        if (s_bail) break;
    }

    // ---- final dense: H(511) in slot 0, blocked-8 layout; cg==0 per bg ----
    if (cg == 0){
        const f16* Hf = H + bg*65536;            // slot 0, this bg's region
        int r = tid >> 2, part = tid & 3;
        float s0 = 0.f, s1 = 0.f;
        for (int cc = 0; cc < 32; cc++){
            int c = part*32 + cc;
            f16x8 h8;
            const f16* hp = Hf + c*512 + r*8;
            asm volatile("global_load_dwordx4 %0, %1, off sc1" : "=v"(h8) : "v"(hp));
            asm volatile("s_waitcnt vmcnt(0)" ::: "memory");
            #pragma unroll
            for (int e = 0; e < 8; e++){
                float hv = (float)h8[e];
                s0 += hv * dw[(size_t)(c*8 + e)*2 + 0];
                s1 += hv * dw[(size_t)(c*8 + e)*2 + 1];
            }
        }
        s0 += __shfl_xor(s0, 1, 64); s0 += __shfl_xor(s0, 2, 64);
        s1 += __shfl_xor(s1, 1, 64); s1 += __shfl_xor(s1, 2, 64);
        if (part == 0){
            int row = bg*64 + r;
            out[(size_t)row*2 + 0] = s0 + db[0];
            out[(size_t)row*2 + 1] = s1 + db[1];
        }
    }
}

extern "C" void kernel_launch(void* const* d_in, const int* in_sizes, int n_in,
                              void* d_out, int out_size, void* d_ws, size_t ws_size,
                              hipStream_t stream)
{
    const int*   tokens = (const int*)d_in[0];
    const float* H0  = (const float*)d_in[1];
    const float* C0  = (const float*)d_in[2];
    const float* Wxi = (const float*)d_in[3];
    const float* Whi = (const float*)d_in[4];
    const float* bi  = (const float*)d_in[5];
    const float* Wxf = (const float*)d_in[6];
    const float* Whf = (const float*)d_in[7];
    const float* bf  = (const float*)d_in[8];
    const float* Wxo = (const float*)d_in[9];
    const float* Who = (const float*)d_in[10];
    const float* bo  = (const float*)d_in[11];
    const float* Wxc = (const float*)d_in[12];
    const float* Whc = (const float*)d_in[13];
    const float* bc  = (const float*)d_in[14];
    const float* emb = (const float*)d_in[15];
    const float* dw  = (const float*)d_in[16];
    const float* db  = (const float*)d_in[17];
    float* out = (float*)d_out;

    char* ws = (char*)d_ws;
    size_t off = 0;
    auto alloc = [&](size_t bytes){ void* p = ws + off; off += (bytes + 255) & ~(size_t)255; return p; };
    f16* WThi = (f16*)alloc((size_t)4096*KTOT*2);
    f16* Xbuf = (f16*)alloc((size_t)STEPS*BATCHN*XPAD*2);
    float* biasP = (float*)alloc(4096*sizeof(float));
    unsigned* flags = (unsigned*)alloc(NBLK*sizeof(unsigned));

    // Ring mode: 64 H slots (33.5MB), fence every 64 steps. Fallback (small
    // ws): 2-slot ping-pong + fence every step (round-9 fingerprint).
    size_t ringBytes = (size_t)64*HSLOT*2;
    int smask, fmask;
    f16* H;
    if (off + ringBytes <= ws_size){
        H = (f16*)alloc(ringBytes);
        smask = 63; fmask = 63;
    } else {
        H = (f16*)alloc((size_t)2*HSLOT*2);
        smask = 1; fmask = 0;
    }
    if (off > ws_size) return;   // workspace too small: fail loud

    hipMemsetAsync(flags, 0, NBLK*sizeof(unsigned), stream);
    pack_w<<<4096, 256, 0, stream>>>(Whi,Whf,Who,Whc, Wxi,Wxf,Wxo,Wxc, bi,bf,bo,bc,
                                     WThi, biasP);
    pack_x<<<STEPS*BATCHN, 128, 0, stream>>>(tokens, emb, Xbuf);
    pack_h0<<<(BATCHN*HID + 255)/256, 256, 0, stream>>>(H0, H);   // slot 0
    lstm_main<<<NBLK, 256, 0, stream>>>(WThi, Xbuf, biasP, C0, H, smask, fmask,
                                        dw, db, out, flags);
}

// Round 16
// 5159.358 us; speedup vs baseline: 2.0572x; 1.0094x over previous
//
#include <hip/hip_runtime.h>

typedef _Float16 f16;
typedef _Float16 f16x8 __attribute__((ext_vector_type(8)));
typedef float f32x4 __attribute__((ext_vector_type(4)));

#define STEPS 512
#define BATCHN 256
#define HID 1024
#define EMBN 100
#define KTOT 1152
#define XPAD 128
#define NBLK 512
#define HSLOT ((size_t)BATCHN*HID)     // f16 elems per H snapshot (512KB)

__device__ __forceinline__ float sigm(float x){ return 1.f/(1.f+__expf(-x)); }
__device__ __forceinline__ float tanh_f(float x){
    float e = __expf(2.f*fabsf(x));
    float r = 1.f - 2.f/(e+1.f);
    return x >= 0.f ? r : -r;
}
// select {a0,a1,a2,a3}[idx] without runtime-indexed array (rule #20)
__device__ __forceinline__ float pick4(float a0, float a1, float a2, float a3, int idx){
    float t0 = (idx & 1) ? a1 : a0;
    float t1 = (idx & 1) ? a3 : a2;
    return (idx & 2) ? t1 : t0;
}

// Pack W_h(1024)+W_x(100)+pad -> WT[4096][1152] f16 hi-only (validated r11).
// Col J = cg*32 + ct*16 + g*4 + um (cg 0..127, ct 0..1) -> unit u = cg*8+ct*4+um.
__global__ void pack_w(const float* __restrict__ Whi_, const float* __restrict__ Whf_,
                       const float* __restrict__ Who_, const float* __restrict__ Whc_,
                       const float* __restrict__ Wxi_, const float* __restrict__ Wxf_,
                       const float* __restrict__ Wxo_, const float* __restrict__ Wxc_,
                       const float* __restrict__ bi_, const float* __restrict__ bf_,
                       const float* __restrict__ bo_, const float* __restrict__ bc_,
                       f16* __restrict__ WThi, float* __restrict__ biasP)
{
    int J = blockIdx.x;                 // 0..4095
    int cg = J >> 5, ct = (J >> 4) & 1, g = (J >> 2) & 3, um = J & 3;
    int u = cg*8 + ct*4 + um;
    const float* Wh = (g==0)?Whi_:(g==1)?Whf_:(g==2)?Who_:Whc_;
    const float* Wx = (g==0)?Wxi_:(g==1)?Wxf_:(g==2)?Wxo_:Wxc_;
    for (int k = threadIdx.x; k < KTOT; k += blockDim.x){
        float v = 0.f;
        if (k < 1024)       v = Wh[(size_t)k*HID + u];
        else if (k < 1124)  v = Wx[(size_t)(k-1024)*HID + u];
        WThi[(size_t)J*KTOT + k] = (f16)v;
    }
    if (threadIdx.x == 0){
        const float* bb = (g==0)?bi_:(g==1)?bf_:(g==2)?bo_:bc_;
        biasP[J] = bb[u];
    }
}

__global__ void pack_x(const int* __restrict__ tokens, const float* __restrict__ emb,
                       f16* __restrict__ Xbuf)
{
    int bid = blockIdx.x;               // t*256 + row
    int t = bid >> 8, row = bid & 255;
    int tok = tokens[(size_t)row*STEPS + t];
    int kx = threadIdx.x;               // 0..127
    float v = (kx < EMBN) ? emb[(size_t)tok*EMBN + kx] : 0.f;
    Xbuf[(size_t)bid*XPAD + kx] = (f16)v;
}

// H0 -> blocked-8 slot-0 layout:
//   elem(row,col) = (row>>6)*65536 + (col>>3)*512 + (row&63)*8 + (col&7)
__global__ void pack_h0(const float* __restrict__ H0, f16* __restrict__ Hb)
{
    int i = blockIdx.x*blockDim.x + threadIdx.x;
    if (i < BATCHN*HID){
        int row = i >> 10, col = i & 1023;
        size_t d = (size_t)(row >> 6)*65536 + (size_t)(col >> 3)*512
                 + (size_t)(row & 63)*8 + (col & 7);
        Hb[d] = (f16)H0[i];
    }
}

// One k-tile's A fragments -> 4 PLAIN cached loads. H in blocked-8 layout:
// chunk = (k>>3)+lhi (8 cols/chunk), within-chunk row offset rloc*8 (16B/row).
// Freshness: ring + fence-every-64 (round-13/14/15 proven protocol).
#define ISSUE(kt_, AF) do {                                                              \
    const int kb_ = w*288 + (kt_)*32;                                                    \
    if (kb_ < 1024) {                                                                    \
        const f16* hb_ = Hrd + ((kb_ >> 3) + lhi)*512;                                   \
        asm volatile("global_load_dwordx4 %0, %1, off" : "=v"(AF[0]) : "v"(hb_ + rS[0])); \
        asm volatile("global_load_dwordx4 %0, %1, off" : "=v"(AF[1]) : "v"(hb_ + rS[1])); \
        asm volatile("global_load_dwordx4 %0, %1, off" : "=v"(AF[2]) : "v"(hb_ + rS[2])); \
        asm volatile("global_load_dwordx4 %0, %1, off" : "=v"(AF[3]) : "v"(hb_ + rS[3])); \
    } else {                                                                             \
        const f16* xb_ = Xrow + (kb_ - 1024) + lhi*8;                                    \
        asm volatile("global_load_dwordx4 %0, %1, off" : "=v"(AF[0]) : "v"(xb_ + rX[0])); \
        asm volatile("global_load_dwordx4 %0, %1, off" : "=v"(AF[1]) : "v"(xb_ + rX[1])); \
        asm volatile("global_load_dwordx4 %0, %1, off" : "=v"(AF[2]) : "v"(xb_ + rX[2])); \
        asm volatile("global_load_dwordx4 %0, %1, off" : "=v"(AF[3]) : "v"(xb_ + rX[3])); \
    }                                                                                    \
} while(0)

// NOTE: wave1 carries one extra outstanding readback load across the step
// boundary. It is always the OLDEST outstanding VMEM op, so vmcnt(N) still
// guarantees the needed A-buffer loads are complete (conservative-safe).
#define WAITK(kt_) do {                                                                  \
    if ((kt_) < 7)       asm volatile("s_waitcnt vmcnt(8)" ::: "memory");                \
    else if ((kt_) == 7) asm volatile("s_waitcnt vmcnt(4)" ::: "memory");                \
    else                 asm volatile("s_waitcnt vmcnt(0)" ::: "memory");                \
    __builtin_amdgcn_sched_barrier(0);                                                   \
} while(0)

// Hi-only MFMA: 4 q-tiles x 2 ct = 8 per k-tile.
#define MM(kt_, AF) do {                                                                 \
    _Pragma("unroll")                                                                    \
    for (int q_ = 0; q_ < 4; q_++){                                                      \
        _Pragma("unroll")                                                                \
        for (int ct_ = 0; ct_ < 2; ct_++){                                               \
            acc[q_][ct_] = __builtin_amdgcn_mfma_f32_16x16x32_f16(AF[q_], Bf[kt_][ct_], acc[q_][ct_], 0,0,0); \
        }                                                                                \
    }                                                                                    \
} while(0)

// Persistent LSTM: 512 blocks (4 bg x 128 cg) x 256 threads, 2 blocks/CU
// (different bgs co-resident -> latency-phase SMT). Weights f16 hi-only in
// AGPR; 12-deep 3-buffer A pipeline; H blocked-8 layout, 64-slot ring, plain
// reads + fence-every-64, coalesced sc1 publish, per-bg flags.
// NEW (r16): after flag store, wave1 READS BACK the block's own published
// 1KB chunk with sc1 loads -> allocates the lines in the LLC so consumers'
// first-touch reads hit LLC (~600cy) instead of HBM (~900cy + tail skew).
__global__ __launch_bounds__(256, 2) void lstm_main(
    const f16* __restrict__ WThi, const f16* __restrict__ Xbuf,
    const float* __restrict__ biasP, const float* __restrict__ C0,
    f16* __restrict__ H, int smask, int fmask,
    const float* __restrict__ dw, const float* __restrict__ db,
    float* __restrict__ out, unsigned* __restrict__ flags)
{
    __shared__ f32x4 red[4*3*2*64];     // [owner4][q1=3][ct2][lane64], 24KB
    __shared__ f16 hstage[64*8];        // block's H tile [64 rows][8 cols], 1KB
    __shared__ int s_bail;

    const int bid = blockIdx.x;
    const int bg = (bid >> 7) & 3, cg = bid & 127;
    const int tid = threadIdx.x;
    const int w = tid >> 6, l = tid & 63, lr = l & 15, lhi = l >> 4;
    const int um = l & 3, gs = lr >> 2;
    if (tid == 0) s_bail = 0;

    // ---- persistent weights: 9 kt x 2 ct = 72 regs/lane (AGPR-resident) ----
    f16x8 Bf[9][2];
    #pragma unroll
    for (int kt = 0; kt < 9; kt++){
        int k0 = w*288 + kt*32 + lhi*8;
        #pragma unroll
        for (int ct = 0; ct < 2; ct++)
            Bf[kt][ct] = *(const f16x8*)(WThi + (size_t)(cg*32 + ct*16 + lr)*KTOT + k0);
    }
    float bs[2][4];                      // [ct][gate]
    #pragma unroll
    for (int ct = 0; ct < 2; ct++)
        #pragma unroll
        for (int g = 0; g < 4; g++)
            bs[ct][g] = biasP[cg*32 + ct*16 + g*4 + um];

    int rS[4], rX[4];
    #pragma unroll
    for (int q = 0; q < 4; q++){
        int rloc = ((w + q) & 3)*16 + lr;
        rS[q] = rloc*8;                  // blocked-8 within-chunk offset
        rX[q] = (bg*64 + rloc)*XPAD;     // row-major Xbuf
    }
    const int myrow0 = bg*64 + w*16 + lhi*4;      // kept rowtile = global rt w

    float Cr[2][4];                      // [ct][r], gs-redundant
    #pragma unroll
    for (int ct = 0; ct < 2; ct++)
        #pragma unroll
        for (int r = 0; r < 4; r++)
            Cr[ct][r] = C0[(size_t)(myrow0 + r)*HID + cg*8 + ct*4 + um];

    __syncthreads();

    for (int t = 0; t < STEPS; t++){
        // ---- window fence (ring reuse): 8 total, proven r13/14/15 ----
        if ((t & fmask) == 0){
            __builtin_amdgcn_fence(__ATOMIC_ACQUIRE, "agent");
            __builtin_amdgcn_sched_barrier(0);
        }

        const f16* Hrd = H + (size_t)(t & smask)*HSLOT + bg*65536;
        f16*       Hwr = H + (size_t)((t + 1) & smask)*HSLOT + bg*65536 + cg*512;
        const f16* Xrow = Xbuf + (size_t)t*BATCHN*XPAD;

        f32x4 acc[4][2];
        #pragma unroll
        for (int q = 0; q < 4; q++)
            #pragma unroll
            for (int ct = 0; ct < 2; ct++) acc[q][ct] = (f32x4){0.f,0.f,0.f,0.f};

        // ---- 12-deep 3-buffer A pipeline (round-4 proven structure) ----
        f16x8 Aa[4], Ab[4], Ac[4];
        ISSUE(0, Aa);
        ISSUE(1, Ab);
        #pragma unroll
        for (int kt = 0; kt < 9; kt++){
            if ((kt % 3) == 0){
                if (kt < 7) ISSUE(kt+2, Ac);
                WAITK(kt); MM(kt, Aa);
            } else if ((kt % 3) == 1){
                if (kt < 7) ISSUE(kt+2, Aa);
                WAITK(kt); MM(kt, Ab);
            } else {
                if (kt < 7) ISSUE(kt+2, Ab);
                WAITK(kt); MM(kt, Ac);
            }
        }

        // ---- cross-wave K reduction (kept tile q=0 <-> global rt w) ----
        #pragma unroll
        for (int q = 1; q < 4; q++){
            int o = (w + q) & 3;
            #pragma unroll
            for (int ct = 0; ct < 2; ct++)
                red[((o*3 + (q-1))*2 + ct)*64 + l] = acc[q][ct];
        }
        __syncthreads();
        #pragma unroll
        for (int q1 = 0; q1 < 3; q1++)
            #pragma unroll
            for (int ct = 0; ct < 2; ct++)
                acc[0][ct] += red[((w*3 + q1)*2 + ct)*64 + l];

        // ---- epilogue: gather gates (xor 4/8/12), update C, h -> LDS tile ----
        #pragma unroll
        for (int ct = 0; ct < 2; ct++){
            #pragma unroll
            for (int r = 0; r < 4; r++){
                float a0 = acc[0][ct][r];
                float a1 = __shfl_xor(a0, 4, 64);
                float a2 = __shfl_xor(a0, 8, 64);
                float a3 = __shfl_xor(a0, 12, 64);
                float gi = pick4(a0,a1,a2,a3, gs    ) + bs[ct][0];
                float gf = pick4(a0,a1,a2,a3, gs ^ 1) + bs[ct][1];
                float go = pick4(a0,a1,a2,a3, gs ^ 2) + bs[ct][2];
                float gc = pick4(a0,a1,a2,a3, gs ^ 3) + bs[ct][3];
                float I = sigm(gi), F = sigm(gf), O = sigm(go), G = tanh_f(gc);
                float c = F*Cr[ct][r] + I*G;
                Cr[ct][r] = c;
                float h = O*tanh_f(c);
                // lane gs owns ct == gs -> (row, col gs*4+um) exactly once
                if (ct == gs)
                    hstage[(w*16 + lhi*4 + r)*8 + gs*4 + um] = (f16)h;
            }
        }
        __syncthreads();

        // ---- publish: 256 x 4B coalesced sc1 stores = 8 full 128B lines ----
        {
            unsigned hv = *(const unsigned*)(hstage + tid*2);
            const f16* dst = Hwr + tid*2;
            asm volatile("global_store_dword %0, %1, off sc1" :: "v"(dst), "v"(hv) : "memory");
        }
        asm volatile("s_waitcnt vmcnt(0)" ::: "memory");
        __syncthreads();

        // ---- flag store, then LLC-prefetch readback of own chunk (wave1) ----
        if (tid == 0)
            __hip_atomic_store(&flags[bg*128 + cg], (unsigned)(t+1), __ATOMIC_RELAXED, __HIP_MEMORY_SCOPE_AGENT);
        if (w == 1){
            // sc1 read-miss allocates the freshly written lines in the LLC so
            // the 127 consumer blocks hit LLC instead of HBM on first touch.
            f16x8 rb;
            const f16* rp = Hwr + (size_t)l*8;
            asm volatile("global_load_dwordx4 %0, %1, off sc1" : "=v"(rb) : "v"(rp));
            asm volatile("" :: "v"(rb));   // keep alive (rule #17); no wait — oldest-op safety
        }

        // ---- per-bg barrier: 128 flags, 2 poll loads per lane ----
        if (w == 0){
            unsigned tgt = (unsigned)(t+1), guard = 0;
            for (;;){
                unsigned f0 = __hip_atomic_load(&flags[bg*128 + l     ], __ATOMIC_RELAXED, __HIP_MEMORY_SCOPE_AGENT);
                unsigned f1 = __hip_atomic_load(&flags[bg*128 + l + 64], __ATOMIC_RELAXED, __HIP_MEMORY_SCOPE_AGENT);
                if (__all((f0 >= tgt) && (f1 >= tgt))) break;
                if (++guard > 2000000u){ s_bail = 1; break; }
                __builtin_amdgcn_s_sleep(1);
            }
        }
        __syncthreads();
        if (s_bail) break;
    }

    // ---- final dense: H(511) in slot 0, blocked-8 layout; cg==0 per bg ----
    if (cg == 0){
        const f16* Hf = H + bg*65536;            // slot 0, this bg's region
        int r = tid >> 2, part = tid & 3;
        float s0 = 0.f, s1 = 0.f;
        for (int cc = 0; cc < 32; cc++){
            int c = part*32 + cc;
            f16x8 h8;
            const f16* hp = Hf + c*512 + r*8;
            asm volatile("global_load_dwordx4 %0, %1, off sc1" : "=v"(h8) : "v"(hp));
            asm volatile("s_waitcnt vmcnt(0)" ::: "memory");
            #pragma unroll
            for (int e = 0; e < 8; e++){
                float hv = (float)h8[e];
                s0 += hv * dw[(size_t)(c*8 + e)*2 + 0];
                s1 += hv * dw[(size_t)(c*8 + e)*2 + 1];
            }
        }
        s0 += __shfl_xor(s0, 1, 64); s0 += __shfl_xor(s0, 2, 64);
        s1 += __shfl_xor(s1, 1, 64); s1 += __shfl_xor(s1, 2, 64);
        if (part == 0){
            int row = bg*64 + r;
            out[(size_t)row*2 + 0] = s0 + db[0];
            out[(size_t)row*2 + 1] = s1 + db[1];
        }
    }
}

extern "C" void kernel_launch(void* const* d_in, const int* in_sizes, int n_in,
                              void* d_out, int out_size, void* d_ws, size_t ws_size,
                              hipStream_t stream)
{
    const int*   tokens = (const int*)d_in[0];
    const float* H0  = (const float*)d_in[1];
    const float* C0  = (const float*)d_in[2];
    const float* Wxi = (const float*)d_in[3];
    const float* Whi = (const float*)d_in[4];
    const float* bi  = (const float*)d_in[5];
    const float* Wxf = (const float*)d_in[6];
    const float* Whf = (const float*)d_in[7];
    const float* bf  = (const float*)d_in[8];
    const float* Wxo = (const float*)d_in[9];
    const float* Who = (const float*)d_in[10];
    const float* bo  = (const float*)d_in[11];
    const float* Wxc = (const float*)d_in[12];
    const float* Whc = (const float*)d_in[13];
    const float* bc  = (const float*)d_in[14];
    const float* emb = (const float*)d_in[15];
    const float* dw  = (const float*)d_in[16];
    const float* db  = (const float*)d_in[17];
    float* out = (float*)d_out;

    char* ws = (char*)d_ws;
    size_t off = 0;
    auto alloc = [&](size_t bytes){ void* p = ws + off; off += (bytes + 255) & ~(size_t)255; return p; };
    f16* WThi = (f16*)alloc((size_t)4096*KTOT*2);
    f16* Xbuf = (f16*)alloc((size_t)STEPS*BATCHN*XPAD*2);
    float* biasP = (float*)alloc(4096*sizeof(float));
    unsigned* flags = (unsigned*)alloc(NBLK*sizeof(unsigned));

    // Ring mode: 64 H slots (33.5MB), fence every 64 steps. Fallback (small
    // ws): 2-slot ping-pong + fence every step (round-9 fingerprint).
    size_t ringBytes = (size_t)64*HSLOT*2;
    int smask, fmask;
    f16* H;
    if (off + ringBytes <= ws_size){
        H = (f16*)alloc(ringBytes);
        smask = 63; fmask = 63;
    } else {
        H = (f16*)alloc((size_t)2*HSLOT*2);
        smask = 1; fmask = 0;
    }
    if (off > ws_size) return;   // workspace too small: fail loud

    hipMemsetAsync(flags, 0, NBLK*sizeof(unsigned), stream);
    pack_w<<<4096, 256, 0, stream>>>(Whi,Whf,Who,Whc, Wxi,Wxf,Wxo,Wxc, bi,bf,bo,bc,
                                     WThi, biasP);
    pack_x<<<STEPS*BATCHN, 128, 0, stream>>>(tokens, emb, Xbuf);
    pack_h0<<<(BATCHN*HID + 255)/256, 256, 0, stream>>>(H0, H);   // slot 0
    lstm_main<<<NBLK, 256, 0, stream>>>(WThi, Xbuf, biasP, C0, H, smask, fmask,
                                        dw, db, out, flags);
}

// Round 17
// 5108.193 us; speedup vs baseline: 2.0778x; 1.0100x over previous
//
#include <hip/hip_runtime.h>

typedef _Float16 f16;
typedef _Float16 f16x8 __attribute__((ext_vector_type(8)));
typedef float f32x4 __attribute__((ext_vector_type(4)));

#define STEPS 512
#define BATCHN 256
#define HID 1024
#define EMBN 100
#define KTOT 1152
#define XPAD 128
#define NBLK 512
#define HSLOT ((size_t)BATCHN*HID)     // f16 elems per H snapshot (512KB)

__device__ __forceinline__ float sigm(float x){ return 1.f/(1.f+__expf(-x)); }
__device__ __forceinline__ float tanh_f(float x){
    float e = __expf(2.f*fabsf(x));
    float r = 1.f - 2.f/(e+1.f);
    return x >= 0.f ? r : -r;
}
// select {a0,a1,a2,a3}[idx] without runtime-indexed array (rule #20)
__device__ __forceinline__ float pick4(float a0, float a1, float a2, float a3, int idx){
    float t0 = (idx & 1) ? a1 : a0;
    float t1 = (idx & 1) ? a3 : a2;
    return (idx & 2) ? t1 : t0;
}

// Pack W_h(1024)+W_x(100)+pad -> WT[4096][1152] f16 hi-only (validated r11).
// Col J = cg*32 + ct*16 + g*4 + um (cg 0..127, ct 0..1) -> unit u = cg*8+ct*4+um.
__global__ void pack_w(const float* __restrict__ Whi_, const float* __restrict__ Whf_,
                       const float* __restrict__ Who_, const float* __restrict__ Whc_,
                       const float* __restrict__ Wxi_, const float* __restrict__ Wxf_,
                       const float* __restrict__ Wxo_, const float* __restrict__ Wxc_,
                       const float* __restrict__ bi_, const float* __restrict__ bf_,
                       const float* __restrict__ bo_, const float* __restrict__ bc_,
                       f16* __restrict__ WThi, float* __restrict__ biasP)
{
    int J = blockIdx.x;                 // 0..4095
    int cg = J >> 5, ct = (J >> 4) & 1, g = (J >> 2) & 3, um = J & 3;
    int u = cg*8 + ct*4 + um;
    const float* Wh = (g==0)?Whi_:(g==1)?Whf_:(g==2)?Who_:Whc_;
    const float* Wx = (g==0)?Wxi_:(g==1)?Wxf_:(g==2)?Wxo_:Wxc_;
    for (int k = threadIdx.x; k < KTOT; k += blockDim.x){
        float v = 0.f;
        if (k < 1024)       v = Wh[(size_t)k*HID + u];
        else if (k < 1124)  v = Wx[(size_t)(k-1024)*HID + u];
        WThi[(size_t)J*KTOT + k] = (f16)v;
    }
    if (threadIdx.x == 0){
        const float* bb = (g==0)?bi_:(g==1)?bf_:(g==2)?bo_:bc_;
        biasP[J] = bb[u];
    }
}

__global__ void pack_x(const int* __restrict__ tokens, const float* __restrict__ emb,
                       f16* __restrict__ Xbuf)
{
    int bid = blockIdx.x;               // t*256 + row
    int t = bid >> 8, row = bid & 255;
    int tok = tokens[(size_t)row*STEPS + t];
    int kx = threadIdx.x;               // 0..127
    float v = (kx < EMBN) ? emb[(size_t)tok*EMBN + kx] : 0.f;
    Xbuf[(size_t)bid*XPAD + kx] = (f16)v;
}

// H0 -> blocked-8 slot-0 layout:
//   elem(row,col) = (row>>6)*65536 + (col>>3)*512 + (row&63)*8 + (col&7)
__global__ void pack_h0(const float* __restrict__ H0, f16* __restrict__ Hb)
{
    int i = blockIdx.x*blockDim.x + threadIdx.x;
    if (i < BATCHN*HID){
        int row = i >> 10, col = i & 1023;
        size_t d = (size_t)(row >> 6)*65536 + (size_t)(col >> 3)*512
                 + (size_t)(row & 63)*8 + (col & 7);
        Hb[d] = (f16)H0[i];
    }
}

// One k-tile's A fragments -> 4 PLAIN cached loads. H in blocked-8 layout:
// chunk = (k>>3)+lhi (8 cols/chunk), within-chunk row offset rloc*8 (16B/row).
// Freshness: ring + fence-every-64 (round-13..16 proven protocol).
#define ISSUE(kt_, AF) do {                                                              \
    const int kb_ = w*288 + (kt_)*32;                                                    \
    if (kb_ < 1024) {                                                                    \
        const f16* hb_ = Hrd + ((kb_ >> 3) + lhi)*512;                                   \
        asm volatile("global_load_dwordx4 %0, %1, off" : "=v"(AF[0]) : "v"(hb_ + rS[0])); \
        asm volatile("global_load_dwordx4 %0, %1, off" : "=v"(AF[1]) : "v"(hb_ + rS[1])); \
        asm volatile("global_load_dwordx4 %0, %1, off" : "=v"(AF[2]) : "v"(hb_ + rS[2])); \
        asm volatile("global_load_dwordx4 %0, %1, off" : "=v"(AF[3]) : "v"(hb_ + rS[3])); \
    } else {                                                                             \
        const f16* xb_ = Xrow + (kb_ - 1024) + lhi*8;                                    \
        asm volatile("global_load_dwordx4 %0, %1, off" : "=v"(AF[0]) : "v"(xb_ + rX[0])); \
        asm volatile("global_load_dwordx4 %0, %1, off" : "=v"(AF[1]) : "v"(xb_ + rX[1])); \
        asm volatile("global_load_dwordx4 %0, %1, off" : "=v"(AF[2]) : "v"(xb_ + rX[2])); \
        asm volatile("global_load_dwordx4 %0, %1, off" : "=v"(AF[3]) : "v"(xb_ + rX[3])); \
    }                                                                                    \
} while(0)

#define WAITK(kt_) do {                                                                  \
    if ((kt_) < 7)       asm volatile("s_waitcnt vmcnt(8)" ::: "memory");                \
    else if ((kt_) == 7) asm volatile("s_waitcnt vmcnt(4)" ::: "memory");                \
    else                 asm volatile("s_waitcnt vmcnt(0)" ::: "memory");                \
    __builtin_amdgcn_sched_barrier(0);                                                   \
} while(0)

// Hi-only MFMA: 4 q-tiles x 2 ct = 8 per k-tile.
#define MM(kt_, AF) do {                                                                 \
    _Pragma("unroll")                                                                    \
    for (int q_ = 0; q_ < 4; q_++){                                                      \
        _Pragma("unroll")                                                                \
        for (int ct_ = 0; ct_ < 2; ct_++){                                               \
            acc[q_][ct_] = __builtin_amdgcn_mfma_f32_16x16x32_f16(AF[q_], Bf[kt_][ct_], acc[q_][ct_], 0,0,0); \
        }                                                                                \
    }                                                                                    \
} while(0)

// Persistent LSTM: 512 blocks (4 bg x 128 cg) x 256 threads, 2 blocks/CU.
// Weights f16 hi-only in AGPR; 12-deep 3-buffer A pipeline; H blocked-8
// layout, 64-slot ring, plain reads + fence-every-64, coalesced sc1 publish.
// NEW (r17): NO global per-step barrier. Each wave waits only on ITS OWN
// <=36 producer chunks (wave w reads K in [w*288,w*288+288) -> chunks
// [w*36, w*36+36)). Transitive deps bound global skew to 1 step (every block
// consumes all 128 chunks), so ring/fence staleness logic is unchanged.
__global__ __launch_bounds__(256, 2) void lstm_main(
    const f16* __restrict__ WThi, const f16* __restrict__ Xbuf,
    const float* __restrict__ biasP, const float* __restrict__ C0,
    f16* __restrict__ H, int smask, int fmask,
    const float* __restrict__ dw, const float* __restrict__ db,
    float* __restrict__ out, unsigned* __restrict__ flags)
{
    __shared__ f32x4 red[4*3*2*64];     // [owner4][q1=3][ct2][lane64], 24KB
    __shared__ f16 hstage[64*8];        // block's H tile [64 rows][8 cols], 1KB
    __shared__ int s_bail;

    const int bid = blockIdx.x;
    const int bg = (bid >> 7) & 3, cg = bid & 127;
    const int tid = threadIdx.x;
    const int w = tid >> 6, l = tid & 63, lr = l & 15, lhi = l >> 4;
    const int um = l & 3, gs = lr >> 2;
    if (tid == 0) s_bail = 0;

    // ---- persistent weights: 9 kt x 2 ct = 72 regs/lane (AGPR-resident) ----
    f16x8 Bf[9][2];
    #pragma unroll
    for (int kt = 0; kt < 9; kt++){
        int k0 = w*288 + kt*32 + lhi*8;
        #pragma unroll
        for (int ct = 0; ct < 2; ct++)
            Bf[kt][ct] = *(const f16x8*)(WThi + (size_t)(cg*32 + ct*16 + lr)*KTOT + k0);
    }
    float bs[2][4];                      // [ct][gate]
    #pragma unroll
    for (int ct = 0; ct < 2; ct++)
        #pragma unroll
        for (int g = 0; g < 4; g++)
            bs[ct][g] = biasP[cg*32 + ct*16 + g*4 + um];

    int rS[4], rX[4];
    #pragma unroll
    for (int q = 0; q < 4; q++){
        int rloc = ((w + q) & 3)*16 + lr;
        rS[q] = rloc*8;                  // blocked-8 within-chunk offset
        rX[q] = (bg*64 + rloc)*XPAD;     // row-major Xbuf
    }
    const int myrow0 = bg*64 + w*16 + lhi*4;      // kept rowtile = global rt w

    // ---- this wave's producer-dependency set: chunks [w*36, w*36+nprod) ----
    const int pbase = w*36;
    const int nprod = (128 - pbase) < 36 ? (128 - pbase) : 36;   // wave3: 20
    const int pidx = bg*128 + pbase + ((l < nprod) ? l : 0);

    float Cr[2][4];                      // [ct][r], gs-redundant
    #pragma unroll
    for (int ct = 0; ct < 2; ct++)
        #pragma unroll
        for (int r = 0; r < 4; r++)
            Cr[ct][r] = C0[(size_t)(myrow0 + r)*HID + cg*8 + ct*4 + um];

    __syncthreads();

    for (int t = 0; t < STEPS; t++){
        // ---- window fence (ring reuse): 8 total, proven r13..16 ----
        if ((t & fmask) == 0){
            __builtin_amdgcn_fence(__ATOMIC_ACQUIRE, "agent");
            __builtin_amdgcn_sched_barrier(0);
        }

        // ---- per-wave producer wait: only MY chunks need flag >= t ----
        {
            unsigned tgt = (unsigned)t, guard = 0;
            for (;;){
                unsigned f0 = __hip_atomic_load(&flags[pidx], __ATOMIC_RELAXED, __HIP_MEMORY_SCOPE_AGENT);
                if (__all(f0 >= tgt)) break;
                if (++guard > 2000000u){ s_bail = 1; break; }
                __builtin_amdgcn_s_sleep(1);
            }
        }

        const f16* Hrd = H + (size_t)(t & smask)*HSLOT + bg*65536;
        f16*       Hwr = H + (size_t)((t + 1) & smask)*HSLOT + bg*65536 + cg*512;
        const f16* Xrow = Xbuf + (size_t)t*BATCHN*XPAD;

        f32x4 acc[4][2];
        #pragma unroll
        for (int q = 0; q < 4; q++)
            #pragma unroll
            for (int ct = 0; ct < 2; ct++) acc[q][ct] = (f32x4){0.f,0.f,0.f,0.f};

        // ---- 12-deep 3-buffer A pipeline (round-4 proven structure) ----
        f16x8 Aa[4], Ab[4], Ac[4];
        ISSUE(0, Aa);
        ISSUE(1, Ab);
        #pragma unroll
        for (int kt = 0; kt < 9; kt++){
            if ((kt % 3) == 0){
                if (kt < 7) ISSUE(kt+2, Ac);
                WAITK(kt); MM(kt, Aa);
            } else if ((kt % 3) == 1){
                if (kt < 7) ISSUE(kt+2, Aa);
                WAITK(kt); MM(kt, Ab);
            } else {
                if (kt < 7) ISSUE(kt+2, Ab);
                WAITK(kt); MM(kt, Ac);
            }
        }

        // ---- cross-wave K reduction (kept tile q=0 <-> global rt w) ----
        #pragma unroll
        for (int q = 1; q < 4; q++){
            int o = (w + q) & 3;
            #pragma unroll
            for (int ct = 0; ct < 2; ct++)
                red[((o*3 + (q-1))*2 + ct)*64 + l] = acc[q][ct];
        }
        __syncthreads();
        if (s_bail) break;               // uniform: all blocks cascade-bail
        #pragma unroll
        for (int q1 = 0; q1 < 3; q1++)
            #pragma unroll
            for (int ct = 0; ct < 2; ct++)
                acc[0][ct] += red[((w*3 + q1)*2 + ct)*64 + l];

        // ---- epilogue: gather gates (xor 4/8/12), update C, h -> LDS tile ----
        #pragma unroll
        for (int ct = 0; ct < 2; ct++){
            #pragma unroll
            for (int r = 0; r < 4; r++){
                float a0 = acc[0][ct][r];
                float a1 = __shfl_xor(a0, 4, 64);
                float a2 = __shfl_xor(a0, 8, 64);
                float a3 = __shfl_xor(a0, 12, 64);
                float gi = pick4(a0,a1,a2,a3, gs    ) + bs[ct][0];
                float gf = pick4(a0,a1,a2,a3, gs ^ 1) + bs[ct][1];
                float go = pick4(a0,a1,a2,a3, gs ^ 2) + bs[ct][2];
                float gc = pick4(a0,a1,a2,a3, gs ^ 3) + bs[ct][3];
                float I = sigm(gi), F = sigm(gf), O = sigm(go), G = tanh_f(gc);
                float c = F*Cr[ct][r] + I*G;
                Cr[ct][r] = c;
                float h = O*tanh_f(c);
                // lane gs owns ct == gs -> (row, col gs*4+um) exactly once
                if (ct == gs)
                    hstage[(w*16 + lhi*4 + r)*8 + gs*4 + um] = (f16)h;
            }
        }
        __syncthreads();

        // ---- publish: 256 x 4B coalesced sc1 stores = 8 full 128B lines ----
        {
            unsigned hv = *(const unsigned*)(hstage + tid*2);
            const f16* dst = Hwr + tid*2;
            asm volatile("global_store_dword %0, %1, off sc1" :: "v"(dst), "v"(hv) : "memory");
        }
        asm volatile("s_waitcnt vmcnt(0)" ::: "memory");
        __syncthreads();

        // ---- announce: own chunk for step t is published (flag = t+1) ----
        if (tid == 0)
            __hip_atomic_store(&flags[bg*128 + cg], (unsigned)(t+1), __ATOMIC_RELAXED, __HIP_MEMORY_SCOPE_AGENT);
    }

    // ---- final dense: needs ALL producers at flag >= STEPS (slot 0 = H(511));
    //      the global barrier that used to guarantee this is gone. ----
    if (cg == 0 && !s_bail){
        if (w == 0){
            unsigned tgt = (unsigned)STEPS, guard = 0;
            for (;;){
                unsigned f0 = __hip_atomic_load(&flags[bg*128 + l     ], __ATOMIC_RELAXED, __HIP_MEMORY_SCOPE_AGENT);
                unsigned f1 = __hip_atomic_load(&flags[bg*128 + l + 64], __ATOMIC_RELAXED, __HIP_MEMORY_SCOPE_AGENT);
                if (__all((f0 >= tgt) && (f1 >= tgt))) break;
                if (++guard > 2000000u){ s_bail = 1; break; }
                __builtin_amdgcn_s_sleep(1);
            }
        }
        __syncthreads();

        const f16* Hf = H + bg*65536;            // slot 0, this bg's region
        int r = tid >> 2, part = tid & 3;
        float s0 = 0.f, s1 = 0.f;
        for (int cc = 0; cc < 32; cc++){
            int c = part*32 + cc;
            f16x8 h8;
            const f16* hp = Hf + c*512 + r*8;
            asm volatile("global_load_dwordx4 %0, %1, off sc1" : "=v"(h8) : "v"(hp));
            asm volatile("s_waitcnt vmcnt(0)" ::: "memory");
            #pragma unroll
            for (int e = 0; e < 8; e++){
                float hv = (float)h8[e];
                s0 += hv * dw[(size_t)(c*8 + e)*2 + 0];
                s1 += hv * dw[(size_t)(c*8 + e)*2 + 1];
            }
        }
        s0 += __shfl_xor(s0, 1, 64); s0 += __shfl_xor(s0, 2, 64);
        s1 += __shfl_xor(s1, 1, 64); s1 += __shfl_xor(s1, 2, 64);
        if (part == 0){
            int row = bg*64 + r;
            out[(size_t)row*2 + 0] = s0 + db[0];
            out[(size_t)row*2 + 1] = s1 + db[1];
        }
    }
}

extern "C" void kernel_launch(void* const* d_in, const int* in_sizes, int n_in,
                              void* d_out, int out_size, void* d_ws, size_t ws_size,
                              hipStream_t stream)
{
    const int*   tokens = (const int*)d_in[0];
    const float* H0  = (const float*)d_in[1];
    const float* C0  = (const float*)d_in[2];
    const float* Wxi = (const float*)d_in[3];
    const float* Whi = (const float*)d_in[4];
    const float* bi  = (const float*)d_in[5];
    const float* Wxf = (const float*)d_in[6];
    const float* Whf = (const float*)d_in[7];
    const float* bf  = (const float*)d_in[8];
    const float* Wxo = (const float*)d_in[9];
    const float* Who = (const float*)d_in[10];
    const float* bo  = (const float*)d_in[11];
    const float* Wxc = (const float*)d_in[12];
    const float* Whc = (const float*)d_in[13];
    const float* bc  = (const float*)d_in[14];
    const float* emb = (const float*)d_in[15];
    const float* dw  = (const float*)d_in[16];
    const float* db  = (const float*)d_in[17];
    float* out = (float*)d_out;

    char* ws = (char*)d_ws;
    size_t off = 0;
    auto alloc = [&](size_t bytes){ void* p = ws + off; off += (bytes + 255) & ~(size_t)255; return p; };
    f16* WThi = (f16*)alloc((size_t)4096*KTOT*2);
    f16* Xbuf = (f16*)alloc((size_t)STEPS*BATCHN*XPAD*2);
    float* biasP = (float*)alloc(4096*sizeof(float));
    unsigned* flags = (unsigned*)alloc(NBLK*sizeof(unsigned));

    // Ring mode: 64 H slots (33.5MB), fence every 64 steps. Fallback (small
    // ws): 2-slot ping-pong + fence every step (round-9 fingerprint).
    size_t ringBytes = (size_t)64*HSLOT*2;
    int smask, fmask;
    f16* H;
    if (off + ringBytes <= ws_size){
        H = (f16*)alloc(ringBytes);
        smask = 63; fmask = 63;
    } else {
        H = (f16*)alloc((size_t)2*HSLOT*2);
        smask = 1; fmask = 0;
    }
    if (off > ws_size) return;   // workspace too small: fail loud

    hipMemsetAsync(flags, 0, NBLK*sizeof(unsigned), stream);
    pack_w<<<4096, 256, 0, stream>>>(Whi,Whf,Who,Whc, Wxi,Wxf,Wxo,Wxc, bi,bf,bo,bc,
                                     WThi, biasP);
    pack_x<<<STEPS*BATCHN, 128, 0, stream>>>(tokens, emb, Xbuf);
    pack_h0<<<(BATCHN*HID + 255)/256, 256, 0, stream>>>(H0, H);   // slot 0
    lstm_main<<<NBLK, 256, 0, stream>>>(WThi, Xbuf, biasP, C0, H, smask, fmask,
                                        dw, db, out, flags);
}